// Round 6
// baseline (160.689 us; speedup 1.0000x reference)
//
#include <hip/hip_runtime.h>
#include <cstdint>
#include <cstddef>

// Problem constants (fixed by reference)
#define SLEN 2048
#define BSZ  2
#define EDIM 1024
#define NHEAD 16
#define DHEAD 64
#define NTOK (SLEN*BSZ)   // 4096

typedef __attribute__((ext_vector_type(8))) short short8;   // 8 x bf16 bits
typedef __attribute__((ext_vector_type(4))) float floatx4;
typedef __attribute__((ext_vector_type(4))) int   int4v;

__device__ __forceinline__ short f2bf(float f) {
  union { float f; uint32_t u; } v; v.f = f;
  uint32_t r = v.u + 0x7fffu + ((v.u >> 16) & 1u);   // round-nearest-even
  return (short)(r >> 16);
}
__device__ __forceinline__ float bf2f(short s) {
  union { uint32_t u; float f; } v; v.u = ((uint32_t)(uint16_t)s) << 16;
  return v.f;
}
__device__ __forceinline__ int q8(float f, float inv) {
  int q = __float2int_rn(f * inv);
  return min(127, max(-127, q));
}
__device__ __forceinline__ void async16(const void* g, void* l) {
  __builtin_amdgcn_global_load_lds((const __attribute__((address_space(1))) void*)g,
                                   (__attribute__((address_space(3))) void*)l,
                                   16, 0, 0);
}
#define VMCNT(n) asm volatile("s_waitcnt vmcnt(" #n ")" ::: "memory")

// ---------------------------------------------------------------------------
// prep2: blocks [0,NTOK): LayerNorm rows -> int8 + per-row scale.
//        blocks [NTOK, NTOK+256): W column-panel (16 cols x full K):
//          z<3 : transpose + col-max + quantize -> w_i8 rows + w_scl
//          z==3: transpose -> Wt bf16 rows (for gemm_o's B^T)
// LDS values are bf16-roundtripped first so w_i8/w_scl are BIT-IDENTICAL to
// the old (transpose->bf16 Wt->quant_w) path.  Replaces old prep + quant_w.
// ---------------------------------------------------------------------------
__global__ __launch_bounds__(256) void prep2(
    const float* __restrict__ x, const float* __restrict__ g,
    const float* __restrict__ b, char* __restrict__ xn_i8,
    float* __restrict__ xn_scl,
    const float* __restrict__ W0, const float* __restrict__ W1,
    const float* __restrict__ W2, const float* __restrict__ W3,
    short* __restrict__ Wt_base, char* __restrict__ w_i8,
    float* __restrict__ w_scl)
{
  __shared__ __align__(16) char smem[1024 * 17 * 4];   // 69632 B
  const int bid = blockIdx.x;
  const int tid = threadIdx.x;

  if (bid < NTOK) {
    // ---------------- LayerNorm (unchanged math) ----------------
    float* ws_s  = (float*)smem;
    float* ws_ss = ws_s + 4;
    float* ws_m  = ws_ss + 4;

    const int row = bid;
    const float4 v = ((const float4*)(x + (size_t)row * EDIM))[tid];
    float s  = v.x + v.y + v.z + v.w;
    float ss = v.x * v.x + v.y * v.y + v.z * v.z + v.w * v.w;
#pragma unroll
    for (int off = 32; off; off >>= 1) {
      s  += __shfl_xor(s, off);
      ss += __shfl_xor(ss, off);
    }
    const int lane = tid & 63, wave = tid >> 6;
    if (lane == 0) { ws_s[wave] = s; ws_ss[wave] = ss; }
    __syncthreads();
    s  = ws_s[0] + ws_s[1] + ws_s[2] + ws_s[3];
    ss = ws_ss[0] + ws_ss[1] + ws_ss[2] + ws_ss[3];

    const float mean = s * (1.0f / EDIM);
    const float var  = ss * (1.0f / EDIM) - mean * mean;
    const float rs   = rsqrtf(var + 1e-5f);

    const float4 gv = ((const float4*)g)[tid];
    const float4 bv = ((const float4*)b)[tid];
    const float n0 = (v.x - mean) * rs * gv.x + bv.x;
    const float n1 = (v.y - mean) * rs * gv.y + bv.y;
    const float n2 = (v.z - mean) * rs * gv.z + bv.z;
    const float n3 = (v.w - mean) * rs * gv.w + bv.w;

    float am = fmaxf(fmaxf(fabsf(n0), fabsf(n1)), fmaxf(fabsf(n2), fabsf(n3)));
#pragma unroll
    for (int off = 32; off; off >>= 1) am = fmaxf(am, __shfl_xor(am, off));
    if (lane == 0) ws_m[wave] = am;
    __syncthreads();
    am = fmaxf(fmaxf(ws_m[0], ws_m[1]), fmaxf(ws_m[2], ws_m[3]));

    const float inv = (am > 1e-30f) ? 127.0f / am : 0.0f;
    const int q0 = q8(n0, inv), q1 = q8(n1, inv), q2 = q8(n2, inv), q3 = q8(n3, inv);
    const uint32_t pack = (uint32_t)(q0 & 0xff) | ((uint32_t)(q1 & 0xff) << 8) |
                          ((uint32_t)(q2 & 0xff) << 16) | ((uint32_t)(q3 & 0xff) << 24);
    ((uint32_t*)(xn_i8 + (size_t)row * EDIM))[tid] = pack;
    if (tid == 0) xn_scl[row] = am * (1.0f / 127.0f);
  } else {
    // ---------------- W column-panel ----------------
    const int pb = bid - NTOK;           // 0..255
    const int z  = pb >> 6;              // 0..3
    const int c0 = (pb & 63) * 16;       // column base
    const float* W = (z == 0) ? W0 : (z == 1) ? W1 : (z == 2) ? W2 : W3;
    float* lds = (float*)smem;           // [1024][17]

    // stage panel W[:, c0..c0+16) -> LDS, bf16-roundtripped
    const int c4 = tid & 3;              // float4 slot in panel
    const int rb = tid >> 2;             // 0..63
#pragma unroll
    for (int i = 0; i < 16; ++i) {
      const int r = rb + i * 64;
      const float4 v = *(const float4*)(W + (size_t)r * EDIM + c0 + c4 * 4);
      float* d = lds + r * 17 + c4 * 4;
      d[0] = bf2f(f2bf(v.x)); d[1] = bf2f(f2bf(v.y));
      d[2] = bf2f(f2bf(v.z)); d[3] = bf2f(f2bf(v.w));
    }
    __syncthreads();

    const int j = tid >> 4;              // column 0..15
    const int l = tid & 15;              // k-slice
    if (z < 3) {
      float am = 0.f;
#pragma unroll 8
      for (int i = 0; i < 64; ++i) {
        const int k = l + 16 * i;
        am = fmaxf(am, fabsf(lds[k * 17 + j]));
      }
#pragma unroll
      for (int off = 1; off <= 8; off <<= 1) am = fmaxf(am, __shfl_xor(am, off));
      const float inv = (am > 1e-30f) ? 127.0f / am : 0.0f;
      char* wrow = w_i8 + ((size_t)z * EDIM + c0 + j) * EDIM;
#pragma unroll
      for (int i = 0; i < 16; ++i) {
        const int k = 4 * l + 64 * i;
        const uint32_t pk =
            (uint32_t)(q8(lds[(k + 0) * 17 + j], inv) & 0xff)        |
            ((uint32_t)(q8(lds[(k + 1) * 17 + j], inv) & 0xff) << 8) |
            ((uint32_t)(q8(lds[(k + 2) * 17 + j], inv) & 0xff) << 16)|
            ((uint32_t)(q8(lds[(k + 3) * 17 + j], inv) & 0xff) << 24);
        *(uint32_t*)(wrow + k) = pk;
      }
      if (l == 0) w_scl[z * EDIM + c0 + j] = am * (1.0f / 127.0f);
    } else {
      short* trow = Wt_base + (size_t)3 * EDIM * EDIM + (size_t)(c0 + j) * EDIM;
#pragma unroll
      for (int i = 0; i < 16; ++i) {
        const int k = 4 * l + 64 * i;
        short4 s4;
        s4.x = f2bf(lds[(k + 0) * 17 + j]);
        s4.y = f2bf(lds[(k + 1) * 17 + j]);
        s4.z = f2bf(lds[(k + 2) * 17 + j]);
        s4.w = f2bf(lds[(k + 3) * 17 + j]);
        *(short4*)(trow + k) = s4;
      }
    }
  }
}

// ---------------------------------------------------------------------------
// QKV projection, W8A8 int8, 256x256 tile, ring-of-4 K-tile pipeline.
// (unchanged — validated, absmax canary held across 4 rounds)
// ---------------------------------------------------------------------------
__global__ __launch_bounds__(512, 2) void gemm_qkv256(
    const char* __restrict__ xn_i8, const float* __restrict__ xn_scl,
    const char* __restrict__ w_i8, const float* __restrict__ w_scl,
    const float* __restrict__ bq, const float* __restrict__ bk,
    const float* __restrict__ bv, short* __restrict__ qkv_base)
{
  __shared__ __align__(16) char lds[4][32768];   // 128 KiB ring

  const int bid = blockIdx.x;                    // 0..191
  const int lin = (bid & 7) * 24 + (bid >> 3);
  const int mt  = lin & 15;
  const int nt  = lin >> 4;
  const int z   = nt >> 2;
  const int bm  = mt * 256;
  const int bnz = (nt & 3) * 256;

  const float* bias = (z == 0) ? bq : (z == 1) ? bk : bv;
  short* out = qkv_base + (size_t)z * NTOK * EDIM;

  const int tid = threadIdx.x;
  const int wv  = tid >> 6;
  const int ln  = tid & 63;
  const int q   = ln >> 4;
  const int l16 = ln & 15;
  const int wm  = wv >> 2;
  const int wn  = wv & 3;

  const int sr = tid >> 2;
  const int sc = ((tid & 3) * 16) ^ ((sr & 3) * 16);
  const char* gA0 = xn_i8 + (size_t)(bm + sr) * EDIM + sc;
  const char* gA1 = gA0 + (size_t)128 * EDIM;
  const char* gB0 = w_i8 + ((size_t)z << 20) + (size_t)(bnz + sr) * EDIM + sc;
  const char* gB1 = gB0 + (size_t)128 * EDIM;
  const int wbase = wv * 1024;

#define QSTAGE(tt) do { \
    char* s_ = lds[(tt) & 3]; \
    async16(gA0 + (tt) * 64, s_ + wbase); \
    async16(gA1 + (tt) * 64, s_ + 8192 + wbase); \
    async16(gB0 + (tt) * 64, s_ + 16384 + wbase); \
    async16(gB1 + (tt) * 64, s_ + 24576 + wbase); \
  } while (0)

  const int swz  = (q * 16) ^ ((l16 & 3) * 16);
  const int aoff = (wm * 128 + l16) * 64 + swz;
  const int boff = 16384 + (wn * 64 + l16) * 64 + swz;

  int4v acc[8][4];
#pragma unroll
  for (int mi = 0; mi < 8; ++mi)
#pragma unroll
    for (int ni = 0; ni < 4; ++ni) { int4v zz = {0,0,0,0}; acc[mi][ni] = zz; }

  QSTAGE(0); QSTAGE(1); QSTAGE(2);
  VMCNT(8);
  __builtin_amdgcn_s_barrier();
  __builtin_amdgcn_sched_barrier(0);

#pragma unroll
  for (int t = 0; t < 16; ++t) {
    if (t + 3 < 16) QSTAGE(t + 3);

    const char* sl = lds[t & 3];
    int4v bf[4], af[8];
#pragma unroll
    for (int ni = 0; ni < 4; ++ni)
      bf[ni] = *(const int4v*)(sl + boff + ni * 1024);
#pragma unroll
    for (int mi = 0; mi < 8; ++mi)
      af[mi] = *(const int4v*)(sl + aoff + mi * 1024);

    __builtin_amdgcn_s_setprio(1);
#pragma unroll
    for (int mi = 0; mi < 8; ++mi)
#pragma unroll
      for (int ni = 0; ni < 4; ++ni)
        acc[mi][ni] = __builtin_amdgcn_mfma_i32_16x16x64_i8(
            af[mi], bf[ni], acc[mi][ni], 0, 0, 0);
    __builtin_amdgcn_s_setprio(0);

    if (t < 15) {
      if (t <= 12)      VMCNT(8);
      else if (t == 13) VMCNT(4);
      else              VMCNT(0);
      __builtin_amdgcn_s_barrier();
      __builtin_amdgcn_sched_barrier(0);
    }
  }
#undef QSTAGE

  const int rbase = bm + wm * 128 + q * 4;
  const int cbl   = bnz + wn * 64 + l16;
#pragma unroll
  for (int mi = 0; mi < 8; ++mi) {
    float sa[4];
#pragma unroll
    for (int r = 0; r < 4; ++r) sa[r] = xn_scl[rbase + mi * 16 + r];
#pragma unroll
    for (int ni = 0; ni < 4; ++ni) {
      const int c  = cbl + ni * 16;
      const float sb = w_scl[z * EDIM + c];
      const float bb = bias[c];
      const int4v v = acc[mi][ni];
#pragma unroll
      for (int r = 0; r < 4; ++r)
        out[(size_t)(rbase + mi * 16 + r) * EDIM + c] =
            f2bf((float)v[r] * (sa[r] * sb) + bb);
    }
  }
}

// ---------------------------------------------------------------------------
// O projection, bf16 MFMA, QKV-geometry (unchanged from round 4).
// ---------------------------------------------------------------------------
__global__ __launch_bounds__(512, 2) void gemm_o128(
    const short* __restrict__ Abf, const short* __restrict__ Bt,
    const float* __restrict__ bo, const float* __restrict__ residual,
    float* __restrict__ out)
{
  __shared__ __align__(16) char lds[4][32768];   // slot: A @0 (16K), B @16384 (16K)

  const int bid = blockIdx.x;
  const int lin = (bid & 7) * 32 + (bid >> 3);   // 0..255
  const int mt  = lin >> 3;                      // 0..31
  const int nt  = lin & 7;                       // 0..7
  const int bm  = mt * 128;
  const int bn  = nt * 128;

  const int tid = threadIdx.x;
  const int wv  = tid >> 6;
  const int ln  = tid & 63;
  const int quad = ln >> 4;
  const int l16  = ln & 15;
  const int wm  = wv >> 2;       // 0..1  (64-row half)
  const int wn  = wv & 3;        // 0..3  (32-col quarter)

  const int sr = tid >> 3;                         // 0..63
  const int sc = ((tid & 7) * 16) ^ ((sr & 7) * 16);
  const char* gA0 = (const char*)Abf + (size_t)(bm + sr) * 2048 + sc;
  const char* gA1 = gA0 + (size_t)64 * 2048;
  const char* gB0 = (const char*)Bt  + (size_t)(bn + sr) * 2048 + sc;
  const char* gB1 = gB0 + (size_t)64 * 2048;
  const int wbase = wv * 1024;

#define OSTAGE(tt) do { \
    char* s_ = lds[(tt) & 3]; \
    async16(gA0 + (tt) * 128, s_ + wbase); \
    async16(gA1 + (tt) * 128, s_ + 8192 + wbase); \
    async16(gB0 + (tt) * 128, s_ + 16384 + wbase); \
    async16(gB1 + (tt) * 128, s_ + 24576 + wbase); \
  } while (0)

  int aoff[2], boff[2];
#pragma unroll
  for (int ks = 0; ks < 2; ++ks) {
    const int c = ks * 64 + quad * 16;
    const int s = (l16 & 7) * 16;
    aoff[ks] = (wm * 64 + l16) * 128 + (c ^ s);
    boff[ks] = 16384 + (wn * 32 + l16) * 128 + (c ^ s);
  }

  floatx4 facc[4][2];
#pragma unroll
  for (int mi = 0; mi < 4; ++mi)
#pragma unroll
    for (int ni = 0; ni < 2; ++ni) { floatx4 zz = {0.f,0.f,0.f,0.f}; facc[mi][ni] = zz; }

  OSTAGE(0); OSTAGE(1); OSTAGE(2);
  VMCNT(8);
  __builtin_amdgcn_s_barrier();
  __builtin_amdgcn_sched_barrier(0);

#pragma unroll
  for (int t = 0; t < 16; ++t) {
    if (t + 3 < 16) OSTAGE(t + 3);

    const char* sl = lds[t & 3];
#pragma unroll
    for (int ks = 0; ks < 2; ++ks) {
      short8 af[4], bf[2];
#pragma unroll
      for (int mi = 0; mi < 4; ++mi)
        af[mi] = *(const short8*)(sl + aoff[ks] + mi * 2048);
#pragma unroll
      for (int ni = 0; ni < 2; ++ni)
        bf[ni] = *(const short8*)(sl + boff[ks] + ni * 2048);

      __builtin_amdgcn_s_setprio(1);
#pragma unroll
      for (int mi = 0; mi < 4; ++mi)
#pragma unroll
        for (int ni = 0; ni < 2; ++ni)
          facc[mi][ni] = __builtin_amdgcn_mfma_f32_16x16x32_bf16(
              af[mi], bf[ni], facc[mi][ni], 0, 0, 0);
      __builtin_amdgcn_s_setprio(0);
    }

    if (t < 15) {
      if (t <= 12)      VMCNT(8);
      else if (t == 13) VMCNT(4);
      else              VMCNT(0);
      __builtin_amdgcn_s_barrier();
      __builtin_amdgcn_sched_barrier(0);
    }
  }
#undef OSTAGE

  const int r0 = bm + wm * 64 + quad * 4;
  const int c0 = bn + wn * 32 + l16;
#pragma unroll
  for (int mi = 0; mi < 4; ++mi)
#pragma unroll
    for (int ni = 0; ni < 2; ++ni) {
      const int col = c0 + ni * 16;
      const float bb = bo[col];
#pragma unroll
      for (int r = 0; r < 4; ++r) {
        const int row = r0 + mi * 16 + r;
        const size_t idx = (size_t)row * EDIM + col;
        out[idx] = residual[idx] + facc[mi][ni][r] + bb;
      }
    }
}

// ---------------------------------------------------------------------------
// MFMA attention (bf16 Q/K/V); writes bf16 output rows directly (unchanged).
// ---------------------------------------------------------------------------
#define VT_LD 80
#define PB_LD 40

__global__ __launch_bounds__(256) void attn_mfma(
    const short* __restrict__ Q, const short* __restrict__ K,
    const short* __restrict__ V, short* __restrict__ Obf)
{
  const int tid  = threadIdx.x;
  const int lane = tid & 63;
  const int wave = tid >> 6;
  const int quad = lane >> 4;
  const int l16  = lane & 15;

  const int bh = blockIdx.y;
  const int h  = bh & (NHEAD - 1);
  const int b  = bh >> 4;
  const int s_blk = blockIdx.x * 64;
  const int col0  = h * DHEAD;

  __shared__ __align__(16) short VT[64 * VT_LD];
  __shared__ __align__(16) short Pb[4][16 * PB_LD];

  for (int task = tid; task < 320; task += 256) {
    const int kp  = task >> 3;
    const int dg  = task & 7;
    const int kk0 = kp * 2;
    int sA = s_blk - 15 + kk0;
    int sB = sA + 1;
    if (sA < 0) sA += SLEN;  if (sA >= SLEN) sA -= SLEN;
    if (sB < 0) sB += SLEN;  if (sB >= SLEN) sB -= SLEN;
    const short8 vA = *(const short8*)(V + (size_t)(sA * BSZ + b) * EDIM + col0 + dg * 8);
    const short8 vB = *(const short8*)(V + (size_t)(sB * BSZ + b) * EDIM + col0 + dg * 8);
#pragma unroll
    for (int j = 0; j < 8; ++j) {
      const int d = dg * 8 + j;
      const uint32_t pack = (uint32_t)(uint16_t)vA[j] | ((uint32_t)(uint16_t)vB[j] << 16);
      *(uint32_t*)&VT[d * VT_LD + kk0] = pack;
    }
  }

  const int sw = s_blk + wave * 16;
  short8 aq[2];
  {
    const size_t base = (size_t)((sw + l16) * BSZ + b) * EDIM + col0 + quad * 8;
    aq[0] = *(const short8*)(Q + base);
    aq[1] = *(const short8*)(Q + base + 32);
  }
  short8 bkf[2][2];
#pragma unroll
  for (int T = 0; T < 2; ++T) {
    int ks = sw - 15 + T * 16 + l16;
    if (ks < 0) ks += SLEN;
    if (ks >= SLEN) ks -= SLEN;
    const size_t base = (size_t)(ks * BSZ + b) * EDIM + col0 + quad * 8;
    bkf[T][0] = *(const short8*)(K + base);
    bkf[T][1] = *(const short8*)(K + base + 32);
  }

  floatx4 S[2];
  { floatx4 zz = {0.f, 0.f, 0.f, 0.f}; S[0] = zz; S[1] = zz; }
#pragma unroll
  for (int T = 0; T < 2; ++T) {
    S[T] = __builtin_amdgcn_mfma_f32_16x16x32_bf16(aq[0], bkf[T][0], S[T], 0, 0, 0);
    S[T] = __builtin_amdgcn_mfma_f32_16x16x32_bf16(aq[1], bkf[T][1], S[T], 0, 0, 0);
  }

  float sc[2][4];
#pragma unroll
  for (int T = 0; T < 2; ++T)
#pragma unroll
    for (int r = 0; r < 4; ++r) {
      const int m = quad * 4 + r;
      const int c = T * 16 + l16;
      const int d = c - m;
      sc[T][r] = (d >= 0 && d <= 15) ? S[T][r] * 0.125f : -1e30f;
    }
  float mx[4], sm[4];
#pragma unroll
  for (int r = 0; r < 4; ++r) mx[r] = fmaxf(sc[0][r], sc[1][r]);
#pragma unroll
  for (int off = 1; off <= 8; off <<= 1)
#pragma unroll
    for (int r = 0; r < 4; ++r) mx[r] = fmaxf(mx[r], __shfl_xor(mx[r], off));
  float p[2][4];
#pragma unroll
  for (int r = 0; r < 4; ++r) {
    p[0][r] = __expf(sc[0][r] - mx[r]);
    p[1][r] = __expf(sc[1][r] - mx[r]);
    sm[r] = p[0][r] + p[1][r];
  }
#pragma unroll
  for (int off = 1; off <= 8; off <<= 1)
#pragma unroll
    for (int r = 0; r < 4; ++r) sm[r] += __shfl_xor(sm[r], off);

  __syncthreads();

  short* Pw = Pb[wave];
#pragma unroll
  for (int T = 0; T < 2; ++T)
#pragma unroll
    for (int r = 0; r < 4; ++r) {
      const int m = quad * 4 + r;
      const int c = T * 16 + l16;
      Pw[m * PB_LD + c] = f2bf(p[T][r]);
    }
  __syncthreads();
  const short8 ap = *(const short8*)(Pw + l16 * PB_LD + quad * 8);

  floatx4 Oacc[4];
  { floatx4 zz = {0.f, 0.f, 0.f, 0.f}; Oacc[0] = zz; Oacc[1] = zz; Oacc[2] = zz; Oacc[3] = zz; }
#pragma unroll
  for (int nt = 0; nt < 4; ++nt) {
    const short8 bv = *(const short8*)(VT + (nt * 16 + l16) * VT_LD + wave * 16 + quad * 8);
    Oacc[nt] = __builtin_amdgcn_mfma_f32_16x16x32_bf16(ap, bv, Oacc[nt], 0, 0, 0);
  }

  float ism[4];
#pragma unroll
  for (int r = 0; r < 4; ++r) ism[r] = 1.0f / sm[r];
#pragma unroll
  for (int nt = 0; nt < 4; ++nt)
#pragma unroll
    for (int r = 0; r < 4; ++r) {
      const int m = quad * 4 + r;
      const int row = (sw + m) * BSZ + b;
      Obf[(size_t)row * EDIM + col0 + nt * 16 + l16] = f2bf(Oacc[nt][r] * ism[r]);
    }
}

// ---------------------------------------------------------------------------
extern "C" void kernel_launch(void* const* d_in, const int* in_sizes, int n_in,
                              void* d_out, int out_size, void* d_ws, size_t ws_size,
                              hipStream_t stream) {
  const float* x    = (const float*)d_in[0];
  const float* ln_g = (const float*)d_in[1];
  const float* ln_b = (const float*)d_in[2];
  const float* Wq   = (const float*)d_in[3];
  const float* bq   = (const float*)d_in[4];
  const float* Wk   = (const float*)d_in[5];
  const float* bk   = (const float*)d_in[6];
  const float* Wv   = (const float*)d_in[7];
  const float* bv   = (const float*)d_in[8];
  const float* Wo   = (const float*)d_in[9];
  const float* bo   = (const float*)d_in[10];
  float* out = (float*)d_out;

  char* ws = (char*)d_ws;
  char*  xn_i8   = ws;                                      // 4 MB (dead after qkv)
  short* Wt      = (short*)(ws + ((size_t)4  << 20));       // z3 @ +10MB live to gemm_o
  char*  w_i8    = ws + ((size_t)12 << 20);                 // 3 MB
  short* QKV     = (short*)(ws + ((size_t)16 << 20));       // 24 MB
  float* xn_scl  = (float*)(ws + ((size_t)44 << 20));       // 16 KB
  float* w_scl   = (float*)(ws + ((size_t)44 << 20) + (1 << 16));
  short* Obf     = (short*)ws;   // 8 MB, overlays xn_i8 + Wt z0/z1 (dead by attn)

  prep2<<<NTOK + 256, 256, 0, stream>>>(x, ln_g, ln_b, xn_i8, xn_scl,
                                        Wq, Wk, Wv, Wo, Wt, w_i8, w_scl);
  gemm_qkv256<<<192, 512, 0, stream>>>(xn_i8, xn_scl, w_i8, w_scl,
                                       bq, bk, bv, QKV);
  attn_mfma<<<dim3(SLEN / 64, BSZ * NHEAD), 256, 0, stream>>>(
      QKV, QKV + (size_t)NTOK * EDIM, QKV + (size_t)2 * NTOK * EDIM, Obf);
  gemm_o128<<<256, 512, 0, stream>>>(
      Obf, Wt + (size_t)3 * EDIM * EDIM, bo, x, out);
}

// Round 7
// 151.631 us; speedup vs baseline: 1.0597x; 1.0597x over previous
//
#include <hip/hip_runtime.h>
#include <cstdint>
#include <cstddef>

// Problem constants (fixed by reference)
#define SLEN 2048
#define BSZ  2
#define EDIM 1024
#define NHEAD 16
#define DHEAD 64
#define NTOK (SLEN*BSZ)   // 4096

typedef __attribute__((ext_vector_type(8))) short short8;   // 8 x bf16 bits
typedef __attribute__((ext_vector_type(4))) float floatx4;
typedef __attribute__((ext_vector_type(4))) int   int4v;

__device__ __forceinline__ short f2bf(float f) {
  union { float f; uint32_t u; } v; v.f = f;
  uint32_t r = v.u + 0x7fffu + ((v.u >> 16) & 1u);   // round-nearest-even
  return (short)(r >> 16);
}
__device__ __forceinline__ float bf2f(short s) {
  union { uint32_t u; float f; } v; v.u = ((uint32_t)(uint16_t)s) << 16;
  return v.f;
}
__device__ __forceinline__ int q8(float f, float inv) {
  int q = __float2int_rn(f * inv);
  return min(127, max(-127, q));
}
__device__ __forceinline__ void async16(const void* g, void* l) {
  __builtin_amdgcn_global_load_lds((const __attribute__((address_space(1))) void*)g,
                                   (__attribute__((address_space(3))) void*)l,
                                   16, 0, 0);
}
#define VMCNT(n) asm volatile("s_waitcnt vmcnt(" #n ")" ::: "memory")

// ---------------------------------------------------------------------------
// prep: blocks [0,NTOK): LayerNorm rows -> int8 + per-row scale.
//       blocks [NTOK, NTOK+4096): weight transpose tiles -> Wt bf16.
// (reverted to the round-5 version — prep2 fusion regressed +12 µs)
// ---------------------------------------------------------------------------
__global__ __launch_bounds__(256) void prep_kernel(
    const float* __restrict__ x, const float* __restrict__ g,
    const float* __restrict__ b, char* __restrict__ xn_i8,
    float* __restrict__ xn_scl,
    const float* __restrict__ W0, const float* __restrict__ W1,
    const float* __restrict__ W2, const float* __restrict__ W3,
    short* __restrict__ Wt_base)
{
  const int bid = blockIdx.x;
  const int tid = threadIdx.x;

  if (bid < NTOK) {
    const int row = bid;
    const float4 v = ((const float4*)(x + (size_t)row * EDIM))[tid];
    float s  = v.x + v.y + v.z + v.w;
    float ss = v.x * v.x + v.y * v.y + v.z * v.z + v.w * v.w;
#pragma unroll
    for (int off = 32; off; off >>= 1) {
      s  += __shfl_xor(s, off);
      ss += __shfl_xor(ss, off);
    }
    __shared__ float ws_s[4], ws_ss[4], ws_m[4];
    const int lane = tid & 63, wave = tid >> 6;
    if (lane == 0) { ws_s[wave] = s; ws_ss[wave] = ss; }
    __syncthreads();
    s  = ws_s[0] + ws_s[1] + ws_s[2] + ws_s[3];
    ss = ws_ss[0] + ws_ss[1] + ws_ss[2] + ws_ss[3];

    const float mean = s * (1.0f / EDIM);
    const float var  = ss * (1.0f / EDIM) - mean * mean;
    const float rs   = rsqrtf(var + 1e-5f);

    const float4 gv = ((const float4*)g)[tid];
    const float4 bv = ((const float4*)b)[tid];
    const float n0 = (v.x - mean) * rs * gv.x + bv.x;
    const float n1 = (v.y - mean) * rs * gv.y + bv.y;
    const float n2 = (v.z - mean) * rs * gv.z + bv.z;
    const float n3 = (v.w - mean) * rs * gv.w + bv.w;

    float am = fmaxf(fmaxf(fabsf(n0), fabsf(n1)), fmaxf(fabsf(n2), fabsf(n3)));
#pragma unroll
    for (int off = 32; off; off >>= 1) am = fmaxf(am, __shfl_xor(am, off));
    if (lane == 0) ws_m[wave] = am;
    __syncthreads();
    am = fmaxf(fmaxf(ws_m[0], ws_m[1]), fmaxf(ws_m[2], ws_m[3]));

    const float inv = (am > 1e-30f) ? 127.0f / am : 0.0f;
    const int q0 = q8(n0, inv), q1 = q8(n1, inv), q2 = q8(n2, inv), q3 = q8(n3, inv);
    const uint32_t pack = (uint32_t)(q0 & 0xff) | ((uint32_t)(q1 & 0xff) << 8) |
                          ((uint32_t)(q2 & 0xff) << 16) | ((uint32_t)(q3 & 0xff) << 24);
    ((uint32_t*)(xn_i8 + (size_t)row * EDIM))[tid] = pack;
    if (tid == 0) xn_scl[row] = am * (1.0f / 127.0f);
  } else {
    const int t = bid - NTOK;
    const int z = t >> 10;
    const int rem = t & 1023;
    const int n0 = (rem & 31) * 32;
    const int k0 = (rem >> 5) * 32;
    const float* W = (z == 0) ? W0 : (z == 1) ? W1 : (z == 2) ? W2 : W3;
    short* Wt = Wt_base + (size_t)z * EDIM * EDIM;

    __shared__ float tile[32][33];
    const int tx = tid & 31;
    const int ty = tid >> 5;
#pragma unroll
    for (int i = 0; i < 4; ++i)
      tile[ty + i * 8][tx] = W[(size_t)(k0 + ty + i * 8) * EDIM + n0 + tx];
    __syncthreads();
#pragma unroll
    for (int i = 0; i < 4; ++i)
      Wt[(size_t)(n0 + ty + i * 8) * EDIM + k0 + tx] = f2bf(tile[tx][ty + i * 8]);
  }
}

// ---------------------------------------------------------------------------
// quant_w: one block per Wt row R (Q,K,V matrices only; Wo stays bf16):
// bf16 -> int8 + per-row (= per output column) scale.
// ---------------------------------------------------------------------------
__global__ __launch_bounds__(256) void quant_w(
    const short* __restrict__ Wt, char* __restrict__ w_i8,
    float* __restrict__ w_scl)
{
  const int R = blockIdx.x;      // 0..3071
  const int tid = threadIdx.x;
  const short4 s4 = ((const short4*)(Wt + (size_t)R * EDIM))[tid];
  const float w0 = bf2f(s4.x), w1 = bf2f(s4.y), w2 = bf2f(s4.z), w3 = bf2f(s4.w);

  float am = fmaxf(fmaxf(fabsf(w0), fabsf(w1)), fmaxf(fabsf(w2), fabsf(w3)));
#pragma unroll
  for (int off = 32; off; off >>= 1) am = fmaxf(am, __shfl_xor(am, off));
  __shared__ float wm[4];
  const int lane = tid & 63, wave = tid >> 6;
  if (lane == 0) wm[wave] = am;
  __syncthreads();
  am = fmaxf(fmaxf(wm[0], wm[1]), fmaxf(wm[2], wm[3]));

  const float inv = (am > 1e-30f) ? 127.0f / am : 0.0f;
  const int q0 = q8(w0, inv), q1 = q8(w1, inv), q2 = q8(w2, inv), q3 = q8(w3, inv);
  const uint32_t pack = (uint32_t)(q0 & 0xff) | ((uint32_t)(q1 & 0xff) << 8) |
                        ((uint32_t)(q2 & 0xff) << 16) | ((uint32_t)(q3 & 0xff) << 24);
  ((uint32_t*)(w_i8 + (size_t)R * EDIM))[tid] = pack;
  if (tid == 0) w_scl[R] = am * (1.0f / 127.0f);
}

// ---------------------------------------------------------------------------
// QKV projection, W8A8 int8, 256x256 tile, ring-of-4 K-tile pipeline.
// (unchanged — validated, absmax canary held across 5 rounds)
// ---------------------------------------------------------------------------
__global__ __launch_bounds__(512, 2) void gemm_qkv256(
    const char* __restrict__ xn_i8, const float* __restrict__ xn_scl,
    const char* __restrict__ w_i8, const float* __restrict__ w_scl,
    const float* __restrict__ bq, const float* __restrict__ bk,
    const float* __restrict__ bv, short* __restrict__ qkv_base)
{
  __shared__ __align__(16) char lds[4][32768];   // 128 KiB ring

  const int bid = blockIdx.x;                    // 0..191
  const int lin = (bid & 7) * 24 + (bid >> 3);
  const int mt  = lin & 15;
  const int nt  = lin >> 4;
  const int z   = nt >> 2;
  const int bm  = mt * 256;
  const int bnz = (nt & 3) * 256;

  const float* bias = (z == 0) ? bq : (z == 1) ? bk : bv;
  short* out = qkv_base + (size_t)z * NTOK * EDIM;

  const int tid = threadIdx.x;
  const int wv  = tid >> 6;
  const int ln  = tid & 63;
  const int q   = ln >> 4;
  const int l16 = ln & 15;
  const int wm  = wv >> 2;
  const int wn  = wv & 3;

  const int sr = tid >> 2;
  const int sc = ((tid & 3) * 16) ^ ((sr & 3) * 16);
  const char* gA0 = xn_i8 + (size_t)(bm + sr) * EDIM + sc;
  const char* gA1 = gA0 + (size_t)128 * EDIM;
  const char* gB0 = w_i8 + ((size_t)z << 20) + (size_t)(bnz + sr) * EDIM + sc;
  const char* gB1 = gB0 + (size_t)128 * EDIM;
  const int wbase = wv * 1024;

#define QSTAGE(tt) do { \
    char* s_ = lds[(tt) & 3]; \
    async16(gA0 + (tt) * 64, s_ + wbase); \
    async16(gA1 + (tt) * 64, s_ + 8192 + wbase); \
    async16(gB0 + (tt) * 64, s_ + 16384 + wbase); \
    async16(gB1 + (tt) * 64, s_ + 24576 + wbase); \
  } while (0)

  const int swz  = (q * 16) ^ ((l16 & 3) * 16);
  const int aoff = (wm * 128 + l16) * 64 + swz;
  const int boff = 16384 + (wn * 64 + l16) * 64 + swz;

  int4v acc[8][4];
#pragma unroll
  for (int mi = 0; mi < 8; ++mi)
#pragma unroll
    for (int ni = 0; ni < 4; ++ni) { int4v zz = {0,0,0,0}; acc[mi][ni] = zz; }

  QSTAGE(0); QSTAGE(1); QSTAGE(2);
  VMCNT(8);
  __builtin_amdgcn_s_barrier();
  __builtin_amdgcn_sched_barrier(0);

#pragma unroll
  for (int t = 0; t < 16; ++t) {
    if (t + 3 < 16) QSTAGE(t + 3);

    const char* sl = lds[t & 3];
    int4v bf[4], af[8];
#pragma unroll
    for (int ni = 0; ni < 4; ++ni)
      bf[ni] = *(const int4v*)(sl + boff + ni * 1024);
#pragma unroll
    for (int mi = 0; mi < 8; ++mi)
      af[mi] = *(const int4v*)(sl + aoff + mi * 1024);

    __builtin_amdgcn_s_setprio(1);
#pragma unroll
    for (int mi = 0; mi < 8; ++mi)
#pragma unroll
      for (int ni = 0; ni < 4; ++ni)
        acc[mi][ni] = __builtin_amdgcn_mfma_i32_16x16x64_i8(
            af[mi], bf[ni], acc[mi][ni], 0, 0, 0);
    __builtin_amdgcn_s_setprio(0);

    if (t < 15) {
      if (t <= 12)      VMCNT(8);
      else if (t == 13) VMCNT(4);
      else              VMCNT(0);
      __builtin_amdgcn_s_barrier();
      __builtin_amdgcn_sched_barrier(0);
    }
  }
#undef QSTAGE

  const int rbase = bm + wm * 128 + q * 4;
  const int cbl   = bnz + wn * 64 + l16;
#pragma unroll
  for (int mi = 0; mi < 8; ++mi) {
    float sa[4];
#pragma unroll
    for (int r = 0; r < 4; ++r) sa[r] = xn_scl[rbase + mi * 16 + r];
#pragma unroll
    for (int ni = 0; ni < 4; ++ni) {
      const int c  = cbl + ni * 16;
      const float sb = w_scl[z * EDIM + c];
      const float bb = bias[c];
      const int4v v = acc[mi][ni];
#pragma unroll
      for (int r = 0; r < 4; ++r)
        out[(size_t)(rbase + mi * 16 + r) * EDIM + c] =
            f2bf((float)v[r] * (sa[r] * sb) + bb);
    }
  }
}

// ---------------------------------------------------------------------------
// O projection, bf16 MFMA, 128x128 tile, ring-of-4 (round-4 K-loop verbatim).
// ROUND 6: coalesced epilogue — stage the f32 C-tile into LDS [128][133],
// then residual-read / bias-read / out-store as float4 per lane (16-lane
// group = 256 B contiguous) instead of 4 B/lane scattered.
// Add order preserved: (residual + c) + bias -> bit-identical output.
// ---------------------------------------------------------------------------
#define CLD 133

__global__ __launch_bounds__(512, 2) void gemm_o128(
    const short* __restrict__ Abf, const short* __restrict__ Bt,
    const float* __restrict__ bo, const float* __restrict__ residual,
    float* __restrict__ out)
{
  __shared__ __align__(16) char lds[4][32768];   // ring; reused as C-tile after loop

  const int bid = blockIdx.x;
  const int lin = (bid & 7) * 32 + (bid >> 3);   // 0..255
  const int mt  = lin >> 3;                      // 0..31
  const int nt  = lin & 7;                       // 0..7
  const int bm  = mt * 128;
  const int bn  = nt * 128;

  const int tid = threadIdx.x;
  const int wv  = tid >> 6;
  const int ln  = tid & 63;
  const int quad = ln >> 4;
  const int l16  = ln & 15;
  const int wm  = wv >> 2;       // 0..1  (64-row half)
  const int wn  = wv & 3;        // 0..3  (32-col quarter)

  const int sr = tid >> 3;                         // 0..63
  const int sc = ((tid & 7) * 16) ^ ((sr & 7) * 16);
  const char* gA0 = (const char*)Abf + (size_t)(bm + sr) * 2048 + sc;
  const char* gA1 = gA0 + (size_t)64 * 2048;
  const char* gB0 = (const char*)Bt  + (size_t)(bn + sr) * 2048 + sc;
  const char* gB1 = gB0 + (size_t)64 * 2048;
  const int wbase = wv * 1024;

#define OSTAGE(tt) do { \
    char* s_ = lds[(tt) & 3]; \
    async16(gA0 + (tt) * 128, s_ + wbase); \
    async16(gA1 + (tt) * 128, s_ + 8192 + wbase); \
    async16(gB0 + (tt) * 128, s_ + 16384 + wbase); \
    async16(gB1 + (tt) * 128, s_ + 24576 + wbase); \
  } while (0)

  int aoff[2], boff[2];
#pragma unroll
  for (int ks = 0; ks < 2; ++ks) {
    const int c = ks * 64 + quad * 16;
    const int s = (l16 & 7) * 16;
    aoff[ks] = (wm * 64 + l16) * 128 + (c ^ s);
    boff[ks] = 16384 + (wn * 32 + l16) * 128 + (c ^ s);
  }

  floatx4 facc[4][2];
#pragma unroll
  for (int mi = 0; mi < 4; ++mi)
#pragma unroll
    for (int ni = 0; ni < 2; ++ni) { floatx4 zz = {0.f,0.f,0.f,0.f}; facc[mi][ni] = zz; }

  OSTAGE(0); OSTAGE(1); OSTAGE(2);
  VMCNT(8);
  __builtin_amdgcn_s_barrier();
  __builtin_amdgcn_sched_barrier(0);

#pragma unroll
  for (int t = 0; t < 16; ++t) {
    if (t + 3 < 16) OSTAGE(t + 3);

    const char* sl = lds[t & 3];
#pragma unroll
    for (int ks = 0; ks < 2; ++ks) {
      short8 af[4], bf[2];
#pragma unroll
      for (int mi = 0; mi < 4; ++mi)
        af[mi] = *(const short8*)(sl + aoff[ks] + mi * 2048);
#pragma unroll
      for (int ni = 0; ni < 2; ++ni)
        bf[ni] = *(const short8*)(sl + boff[ks] + ni * 2048);

      __builtin_amdgcn_s_setprio(1);
#pragma unroll
      for (int mi = 0; mi < 4; ++mi)
#pragma unroll
        for (int ni = 0; ni < 2; ++ni)
          facc[mi][ni] = __builtin_amdgcn_mfma_f32_16x16x32_bf16(
              af[mi], bf[ni], facc[mi][ni], 0, 0, 0);
      __builtin_amdgcn_s_setprio(0);
    }

    if (t < 15) {
      if (t <= 12)      VMCNT(8);
      else if (t == 13) VMCNT(4);
      else              VMCNT(0);
      __builtin_amdgcn_s_barrier();
      __builtin_amdgcn_sched_barrier(0);
    }
  }
#undef OSTAGE

  // ---- coalesced epilogue: C-tile -> LDS f32 [128][CLD], then float4 I/O
  __syncthreads();                               // all ds_reads of ring done
  float* Cf = (float*)lds;
#pragma unroll
  for (int mi = 0; mi < 4; ++mi)
#pragma unroll
    for (int ni = 0; ni < 2; ++ni) {
      const int rl = wm * 64 + mi * 16 + quad * 4;
      const int cl = wn * 32 + ni * 16 + l16;
#pragma unroll
      for (int r = 0; r < 4; ++r)
        Cf[(rl + r) * CLD + cl] = facc[mi][ni][r];
    }
  __syncthreads();

  const int rg  = tid >> 4;            // 0..31 (row group)
  const int cl4 = (tid & 15) * 4;      // float4 col within a 64-col pass
#pragma unroll
  for (int jj = 0; jj < 4; ++jj) {
    const int rl = rg + jj * 32;       // 0..127
    const float* rrow = residual + (size_t)(bm + rl) * EDIM + bn;
    float*       orow = out      + (size_t)(bm + rl) * EDIM + bn;
#pragma unroll
    for (int cp = 0; cp < 2; ++cp) {
      const int col = cp * 64 + cl4;
      const float4 c   = *(const float4*)(Cf + rl * CLD + col);
      const float4 rsd = *(const float4*)(rrow + col);
      const float4 bb4 = *(const float4*)(bo + bn + col);
      float4 o;
      o.x = rsd.x + c.x + bb4.x;
      o.y = rsd.y + c.y + bb4.y;
      o.z = rsd.z + c.z + bb4.z;
      o.w = rsd.w + c.w + bb4.w;
      *(float4*)(orow + col) = o;
    }
  }
}

// ---------------------------------------------------------------------------
// MFMA attention (bf16 Q/K/V); writes bf16 output rows directly (unchanged).
// ---------------------------------------------------------------------------
#define VT_LD 80
#define PB_LD 40

__global__ __launch_bounds__(256) void attn_mfma(
    const short* __restrict__ Q, const short* __restrict__ K,
    const short* __restrict__ V, short* __restrict__ Obf)
{
  const int tid  = threadIdx.x;
  const int lane = tid & 63;
  const int wave = tid >> 6;
  const int quad = lane >> 4;
  const int l16  = lane & 15;

  const int bh = blockIdx.y;
  const int h  = bh & (NHEAD - 1);
  const int b  = bh >> 4;
  const int s_blk = blockIdx.x * 64;
  const int col0  = h * DHEAD;

  __shared__ __align__(16) short VT[64 * VT_LD];
  __shared__ __align__(16) short Pb[4][16 * PB_LD];

  for (int task = tid; task < 320; task += 256) {
    const int kp  = task >> 3;
    const int dg  = task & 7;
    const int kk0 = kp * 2;
    int sA = s_blk - 15 + kk0;
    int sB = sA + 1;
    if (sA < 0) sA += SLEN;  if (sA >= SLEN) sA -= SLEN;
    if (sB < 0) sB += SLEN;  if (sB >= SLEN) sB -= SLEN;
    const short8 vA = *(const short8*)(V + (size_t)(sA * BSZ + b) * EDIM + col0 + dg * 8);
    const short8 vB = *(const short8*)(V + (size_t)(sB * BSZ + b) * EDIM + col0 + dg * 8);
#pragma unroll
    for (int j = 0; j < 8; ++j) {
      const int d = dg * 8 + j;
      const uint32_t pack = (uint32_t)(uint16_t)vA[j] | ((uint32_t)(uint16_t)vB[j] << 16);
      *(uint32_t*)&VT[d * VT_LD + kk0] = pack;
    }
  }

  const int sw = s_blk + wave * 16;
  short8 aq[2];
  {
    const size_t base = (size_t)((sw + l16) * BSZ + b) * EDIM + col0 + quad * 8;
    aq[0] = *(const short8*)(Q + base);
    aq[1] = *(const short8*)(Q + base + 32);
  }
  short8 bkf[2][2];
#pragma unroll
  for (int T = 0; T < 2; ++T) {
    int ks = sw - 15 + T * 16 + l16;
    if (ks < 0) ks += SLEN;
    if (ks >= SLEN) ks -= SLEN;
    const size_t base = (size_t)(ks * BSZ + b) * EDIM + col0 + quad * 8;
    bkf[T][0] = *(const short8*)(K + base);
    bkf[T][1] = *(const short8*)(K + base + 32);
  }

  floatx4 S[2];
  { floatx4 zz = {0.f, 0.f, 0.f, 0.f}; S[0] = zz; S[1] = zz; }
#pragma unroll
  for (int T = 0; T < 2; ++T) {
    S[T] = __builtin_amdgcn_mfma_f32_16x16x32_bf16(aq[0], bkf[T][0], S[T], 0, 0, 0);
    S[T] = __builtin_amdgcn_mfma_f32_16x16x32_bf16(aq[1], bkf[T][1], S[T], 0, 0, 0);
  }

  float sc[2][4];
#pragma unroll
  for (int T = 0; T < 2; ++T)
#pragma unroll
    for (int r = 0; r < 4; ++r) {
      const int m = quad * 4 + r;
      const int c = T * 16 + l16;
      const int d = c - m;
      sc[T][r] = (d >= 0 && d <= 15) ? S[T][r] * 0.125f : -1e30f;
    }
  float mx[4], sm[4];
#pragma unroll
  for (int r = 0; r < 4; ++r) mx[r] = fmaxf(sc[0][r], sc[1][r]);
#pragma unroll
  for (int off = 1; off <= 8; off <<= 1)
#pragma unroll
    for (int r = 0; r < 4; ++r) mx[r] = fmaxf(mx[r], __shfl_xor(mx[r], off));
  float p[2][4];
#pragma unroll
  for (int r = 0; r < 4; ++r) {
    p[0][r] = __expf(sc[0][r] - mx[r]);
    p[1][r] = __expf(sc[1][r] - mx[r]);
    sm[r] = p[0][r] + p[1][r];
  }
#pragma unroll
  for (int off = 1; off <= 8; off <<= 1)
#pragma unroll
    for (int r = 0; r < 4; ++r) sm[r] += __shfl_xor(sm[r], off);

  __syncthreads();

  short* Pw = Pb[wave];
#pragma unroll
  for (int T = 0; T < 2; ++T)
#pragma unroll
    for (int r = 0; r < 4; ++r) {
      const int m = quad * 4 + r;
      const int c = T * 16 + l16;
      Pw[m * PB_LD + c] = f2bf(p[T][r]);
    }
  __syncthreads();
  const short8 ap = *(const short8*)(Pw + l16 * PB_LD + quad * 8);

  floatx4 Oacc[4];
  { floatx4 zz = {0.f, 0.f, 0.f, 0.f}; Oacc[0] = zz; Oacc[1] = zz; Oacc[2] = zz; Oacc[3] = zz; }
#pragma unroll
  for (int nt = 0; nt < 4; ++nt) {
    const short8 bv = *(const short8*)(VT + (nt * 16 + l16) * VT_LD + wave * 16 + quad * 8);
    Oacc[nt] = __builtin_amdgcn_mfma_f32_16x16x32_bf16(ap, bv, Oacc[nt], 0, 0, 0);
  }

  float ism[4];
#pragma unroll
  for (int r = 0; r < 4; ++r) ism[r] = 1.0f / sm[r];
#pragma unroll
  for (int nt = 0; nt < 4; ++nt)
#pragma unroll
    for (int r = 0; r < 4; ++r) {
      const int m = quad * 4 + r;
      const int row = (sw + m) * BSZ + b;
      Obf[(size_t)row * EDIM + col0 + nt * 16 + l16] = f2bf(Oacc[nt][r] * ism[r]);
    }
}

// ---------------------------------------------------------------------------
extern "C" void kernel_launch(void* const* d_in, const int* in_sizes, int n_in,
                              void* d_out, int out_size, void* d_ws, size_t ws_size,
                              hipStream_t stream) {
  const float* x    = (const float*)d_in[0];
  const float* ln_g = (const float*)d_in[1];
  const float* ln_b = (const float*)d_in[2];
  const float* Wq   = (const float*)d_in[3];
  const float* bq   = (const float*)d_in[4];
  const float* Wk   = (const float*)d_in[5];
  const float* bk   = (const float*)d_in[6];
  const float* Wv   = (const float*)d_in[7];
  const float* bv   = (const float*)d_in[8];
  const float* Wo   = (const float*)d_in[9];
  const float* bo   = (const float*)d_in[10];
  float* out = (float*)d_out;

  char* ws = (char*)d_ws;
  char*  xn_i8   = ws;                                      // 4 MB (dead after qkv)
  short* Wt      = (short*)(ws + ((size_t)4  << 20));       // 8 MB (z3 live to gemm_o)
  char*  w_i8    = ws + ((size_t)12 << 20);                 // 3 MB
  short* QKV     = (short*)(ws + ((size_t)16 << 20));       // 24 MB
  float* xn_scl  = (float*)(ws + ((size_t)44 << 20));       // 16 KB
  float* w_scl   = (float*)(ws + ((size_t)44 << 20) + (1 << 16));
  short* Obf     = (short*)ws;   // 8 MB, overlays xn_i8 + Wt z0/z1 (dead by attn)

  prep_kernel<<<NTOK + 4096, 256, 0, stream>>>(x, ln_g, ln_b, xn_i8, xn_scl,
                                               Wq, Wk, Wv, Wo, Wt);
  quant_w<<<3 * EDIM, 256, 0, stream>>>(Wt, w_i8, w_scl);
  gemm_qkv256<<<192, 512, 0, stream>>>(xn_i8, xn_scl, w_i8, w_scl,
                                       bq, bk, bv, QKV);
  attn_mfma<<<dim3(SLEN / 64, BSZ * NHEAD), 256, 0, stream>>>(
      QKV, QKV + (size_t)NTOK * EDIM, QKV + (size_t)2 * NTOK * EDIM, Obf);
  gemm_o128<<<256, 512, 0, stream>>>(
      Obf, Wt + (size_t)3 * EDIM * EDIM, bo, x, out);
}

// Round 8
// 150.260 us; speedup vs baseline: 1.0694x; 1.0091x over previous
//
#include <hip/hip_runtime.h>
#include <cstdint>
#include <cstddef>

// Problem constants (fixed by reference)
#define SLEN 2048
#define BSZ  2
#define EDIM 1024
#define NHEAD 16
#define DHEAD 64
#define NTOK (SLEN*BSZ)   // 4096

typedef __attribute__((ext_vector_type(8))) short short8;   // 8 x bf16 bits
typedef __attribute__((ext_vector_type(4))) float floatx4;
typedef __attribute__((ext_vector_type(4))) int   int4v;

__device__ __forceinline__ short f2bf(float f) {
  union { float f; uint32_t u; } v; v.f = f;
  uint32_t r = v.u + 0x7fffu + ((v.u >> 16) & 1u);   // round-nearest-even
  return (short)(r >> 16);
}
__device__ __forceinline__ float bf2f(short s) {
  union { uint32_t u; float f; } v; v.u = ((uint32_t)(uint16_t)s) << 16;
  return v.f;
}
__device__ __forceinline__ int q8(float f, float inv) {
  int q = __float2int_rn(f * inv);
  return min(127, max(-127, q));
}
__device__ __forceinline__ void async16(const void* g, void* l) {
  __builtin_amdgcn_global_load_lds((const __attribute__((address_space(1))) void*)g,
                                   (__attribute__((address_space(3))) void*)l,
                                   16, 0, 0);
}
#define VMCNT(n) asm volatile("s_waitcnt vmcnt(" #n ")" ::: "memory")

// ---------------------------------------------------------------------------
// prep: blocks [0,NTOK): LayerNorm rows -> int8 + per-row scale.
//       blocks [NTOK, NTOK+1024): 64x64 weight transpose tiles -> Wt bf16.
// ROUND 7: transpose upgraded 32x32 -> 64x64 tiles: 256 B-contig f32 reads,
// 128 B-contig bf16 writes (2x granule both sides), 1024 blocks not 4096.
// Element-wise identical output (same f2bf per element).
// ---------------------------------------------------------------------------
__global__ __launch_bounds__(256) void prep_kernel(
    const float* __restrict__ x, const float* __restrict__ g,
    const float* __restrict__ b, char* __restrict__ xn_i8,
    float* __restrict__ xn_scl,
    const float* __restrict__ W0, const float* __restrict__ W1,
    const float* __restrict__ W2, const float* __restrict__ W3,
    short* __restrict__ Wt_base)
{
  const int bid = blockIdx.x;
  const int tid = threadIdx.x;

  if (bid < NTOK) {
    const int row = bid;
    const float4 v = ((const float4*)(x + (size_t)row * EDIM))[tid];
    float s  = v.x + v.y + v.z + v.w;
    float ss = v.x * v.x + v.y * v.y + v.z * v.z + v.w * v.w;
#pragma unroll
    for (int off = 32; off; off >>= 1) {
      s  += __shfl_xor(s, off);
      ss += __shfl_xor(ss, off);
    }
    __shared__ float ws_s[4], ws_ss[4], ws_m[4];
    const int lane = tid & 63, wave = tid >> 6;
    if (lane == 0) { ws_s[wave] = s; ws_ss[wave] = ss; }
    __syncthreads();
    s  = ws_s[0] + ws_s[1] + ws_s[2] + ws_s[3];
    ss = ws_ss[0] + ws_ss[1] + ws_ss[2] + ws_ss[3];

    const float mean = s * (1.0f / EDIM);
    const float var  = ss * (1.0f / EDIM) - mean * mean;
    const float rs   = rsqrtf(var + 1e-5f);

    const float4 gv = ((const float4*)g)[tid];
    const float4 bv = ((const float4*)b)[tid];
    const float n0 = (v.x - mean) * rs * gv.x + bv.x;
    const float n1 = (v.y - mean) * rs * gv.y + bv.y;
    const float n2 = (v.z - mean) * rs * gv.z + bv.z;
    const float n3 = (v.w - mean) * rs * gv.w + bv.w;

    float am = fmaxf(fmaxf(fabsf(n0), fabsf(n1)), fmaxf(fabsf(n2), fabsf(n3)));
#pragma unroll
    for (int off = 32; off; off >>= 1) am = fmaxf(am, __shfl_xor(am, off));
    if (lane == 0) ws_m[wave] = am;
    __syncthreads();
    am = fmaxf(fmaxf(ws_m[0], ws_m[1]), fmaxf(ws_m[2], ws_m[3]));

    const float inv = (am > 1e-30f) ? 127.0f / am : 0.0f;
    const int q0 = q8(n0, inv), q1 = q8(n1, inv), q2 = q8(n2, inv), q3 = q8(n3, inv);
    const uint32_t pack = (uint32_t)(q0 & 0xff) | ((uint32_t)(q1 & 0xff) << 8) |
                          ((uint32_t)(q2 & 0xff) << 16) | ((uint32_t)(q3 & 0xff) << 24);
    ((uint32_t*)(xn_i8 + (size_t)row * EDIM))[tid] = pack;
    if (tid == 0) xn_scl[row] = am * (1.0f / 127.0f);
  } else {
    // ---- 64x64 transpose tile ----
    const int t   = bid - NTOK;          // 0..1023
    const int z   = t >> 8;              // 0..3
    const int rem = t & 255;
    const int n0  = (rem & 15) * 64;
    const int k0  = (rem >> 4) * 64;
    const float* W = (z == 0) ? W0 : (z == 1) ? W1 : (z == 2) ? W2 : W3;
    short* Wt = Wt_base + (size_t)z * EDIM * EDIM;

    __shared__ float tile[64][65];       // pad 65: 2-way bank alias (free)
    const int tx = tid & 15;
    const int ty = tid >> 4;             // 0..15
#pragma unroll
    for (int i = 0; i < 4; ++i) {
      const float4 v = *(const float4*)(W + (size_t)(k0 + ty + 16 * i) * EDIM + n0 + tx * 4);
      float* d = &tile[ty + 16 * i][tx * 4];
      d[0] = v.x; d[1] = v.y; d[2] = v.z; d[3] = v.w;
    }
    __syncthreads();
#pragma unroll
    for (int i = 0; i < 4; ++i) {
      short4 s4;
      s4.x = f2bf(tile[tx * 4 + 0][ty + 16 * i]);
      s4.y = f2bf(tile[tx * 4 + 1][ty + 16 * i]);
      s4.z = f2bf(tile[tx * 4 + 2][ty + 16 * i]);
      s4.w = f2bf(tile[tx * 4 + 3][ty + 16 * i]);
      *(short4*)(Wt + (size_t)(n0 + ty + 16 * i) * EDIM + k0 + tx * 4) = s4;
    }
  }
}

// ---------------------------------------------------------------------------
// quant_w: one block per Wt row R (Q,K,V matrices only; Wo stays bf16):
// bf16 -> int8 + per-row (= per output column) scale.
// ---------------------------------------------------------------------------
__global__ __launch_bounds__(256) void quant_w(
    const short* __restrict__ Wt, char* __restrict__ w_i8,
    float* __restrict__ w_scl)
{
  const int R = blockIdx.x;      // 0..3071
  const int tid = threadIdx.x;
  const short4 s4 = ((const short4*)(Wt + (size_t)R * EDIM))[tid];
  const float w0 = bf2f(s4.x), w1 = bf2f(s4.y), w2 = bf2f(s4.z), w3 = bf2f(s4.w);

  float am = fmaxf(fmaxf(fabsf(w0), fabsf(w1)), fmaxf(fabsf(w2), fabsf(w3)));
#pragma unroll
  for (int off = 32; off; off >>= 1) am = fmaxf(am, __shfl_xor(am, off));
  __shared__ float wm[4];
  const int lane = tid & 63, wave = tid >> 6;
  if (lane == 0) wm[wave] = am;
  __syncthreads();
  am = fmaxf(fmaxf(wm[0], wm[1]), fmaxf(wm[2], wm[3]));

  const float inv = (am > 1e-30f) ? 127.0f / am : 0.0f;
  const int q0 = q8(w0, inv), q1 = q8(w1, inv), q2 = q8(w2, inv), q3 = q8(w3, inv);
  const uint32_t pack = (uint32_t)(q0 & 0xff) | ((uint32_t)(q1 & 0xff) << 8) |
                        ((uint32_t)(q2 & 0xff) << 16) | ((uint32_t)(q3 & 0xff) << 24);
  ((uint32_t*)(w_i8 + (size_t)R * EDIM))[tid] = pack;
  if (tid == 0) w_scl[R] = am * (1.0f / 127.0f);
}

// ---------------------------------------------------------------------------
// QKV projection, W8A8 int8, 256x256 tile, ring-of-4 K-tile pipeline.
// (unchanged — validated, absmax canary held across 6 rounds)
// ---------------------------------------------------------------------------
__global__ __launch_bounds__(512, 2) void gemm_qkv256(
    const char* __restrict__ xn_i8, const float* __restrict__ xn_scl,
    const char* __restrict__ w_i8, const float* __restrict__ w_scl,
    const float* __restrict__ bq, const float* __restrict__ bk,
    const float* __restrict__ bv, short* __restrict__ qkv_base)
{
  __shared__ __align__(16) char lds[4][32768];   // 128 KiB ring

  const int bid = blockIdx.x;                    // 0..191
  const int lin = (bid & 7) * 24 + (bid >> 3);
  const int mt  = lin & 15;
  const int nt  = lin >> 4;
  const int z   = nt >> 2;
  const int bm  = mt * 256;
  const int bnz = (nt & 3) * 256;

  const float* bias = (z == 0) ? bq : (z == 1) ? bk : bv;
  short* out = qkv_base + (size_t)z * NTOK * EDIM;

  const int tid = threadIdx.x;
  const int wv  = tid >> 6;
  const int ln  = tid & 63;
  const int q   = ln >> 4;
  const int l16 = ln & 15;
  const int wm  = wv >> 2;
  const int wn  = wv & 3;

  const int sr = tid >> 2;
  const int sc = ((tid & 3) * 16) ^ ((sr & 3) * 16);
  const char* gA0 = xn_i8 + (size_t)(bm + sr) * EDIM + sc;
  const char* gA1 = gA0 + (size_t)128 * EDIM;
  const char* gB0 = w_i8 + ((size_t)z << 20) + (size_t)(bnz + sr) * EDIM + sc;
  const char* gB1 = gB0 + (size_t)128 * EDIM;
  const int wbase = wv * 1024;

#define QSTAGE(tt) do { \
    char* s_ = lds[(tt) & 3]; \
    async16(gA0 + (tt) * 64, s_ + wbase); \
    async16(gA1 + (tt) * 64, s_ + 8192 + wbase); \
    async16(gB0 + (tt) * 64, s_ + 16384 + wbase); \
    async16(gB1 + (tt) * 64, s_ + 24576 + wbase); \
  } while (0)

  const int swz  = (q * 16) ^ ((l16 & 3) * 16);
  const int aoff = (wm * 128 + l16) * 64 + swz;
  const int boff = 16384 + (wn * 64 + l16) * 64 + swz;

  int4v acc[8][4];
#pragma unroll
  for (int mi = 0; mi < 8; ++mi)
#pragma unroll
    for (int ni = 0; ni < 4; ++ni) { int4v zz = {0,0,0,0}; acc[mi][ni] = zz; }

  QSTAGE(0); QSTAGE(1); QSTAGE(2);
  VMCNT(8);
  __builtin_amdgcn_s_barrier();
  __builtin_amdgcn_sched_barrier(0);

#pragma unroll
  for (int t = 0; t < 16; ++t) {
    if (t + 3 < 16) QSTAGE(t + 3);

    const char* sl = lds[t & 3];
    int4v bf[4], af[8];
#pragma unroll
    for (int ni = 0; ni < 4; ++ni)
      bf[ni] = *(const int4v*)(sl + boff + ni * 1024);
#pragma unroll
    for (int mi = 0; mi < 8; ++mi)
      af[mi] = *(const int4v*)(sl + aoff + mi * 1024);

    __builtin_amdgcn_s_setprio(1);
#pragma unroll
    for (int mi = 0; mi < 8; ++mi)
#pragma unroll
      for (int ni = 0; ni < 4; ++ni)
        acc[mi][ni] = __builtin_amdgcn_mfma_i32_16x16x64_i8(
            af[mi], bf[ni], acc[mi][ni], 0, 0, 0);
    __builtin_amdgcn_s_setprio(0);

    if (t < 15) {
      if (t <= 12)      VMCNT(8);
      else if (t == 13) VMCNT(4);
      else              VMCNT(0);
      __builtin_amdgcn_s_barrier();
      __builtin_amdgcn_sched_barrier(0);
    }
  }
#undef QSTAGE

  const int rbase = bm + wm * 128 + q * 4;
  const int cbl   = bnz + wn * 64 + l16;
#pragma unroll
  for (int mi = 0; mi < 8; ++mi) {
    float sa[4];
#pragma unroll
    for (int r = 0; r < 4; ++r) sa[r] = xn_scl[rbase + mi * 16 + r];
#pragma unroll
    for (int ni = 0; ni < 4; ++ni) {
      const int c  = cbl + ni * 16;
      const float sb = w_scl[z * EDIM + c];
      const float bb = bias[c];
      const int4v v = acc[mi][ni];
#pragma unroll
      for (int r = 0; r < 4; ++r)
        out[(size_t)(rbase + mi * 16 + r) * EDIM + c] =
            f2bf((float)v[r] * (sa[r] * sb) + bb);
    }
  }
}

// ---------------------------------------------------------------------------
// O projection, bf16 MFMA, 128x128 tile, ring-of-4 (round-4 version verbatim
// — the R6 LDS-staged epilogue regressed and is reverted).
// ---------------------------------------------------------------------------
__global__ __launch_bounds__(512, 2) void gemm_o128(
    const short* __restrict__ Abf, const short* __restrict__ Bt,
    const float* __restrict__ bo, const float* __restrict__ residual,
    float* __restrict__ out)
{
  __shared__ __align__(16) char lds[4][32768];   // slot: A @0 (16K), B @16384 (16K)

  const int bid = blockIdx.x;
  const int lin = (bid & 7) * 32 + (bid >> 3);   // 0..255
  const int mt  = lin >> 3;                      // 0..31
  const int nt  = lin & 7;                       // 0..7
  const int bm  = mt * 128;
  const int bn  = nt * 128;

  const int tid = threadIdx.x;
  const int wv  = tid >> 6;
  const int ln  = tid & 63;
  const int quad = ln >> 4;
  const int l16  = ln & 15;
  const int wm  = wv >> 2;       // 0..1  (64-row half)
  const int wn  = wv & 3;        // 0..3  (32-col quarter)

  const int sr = tid >> 3;                         // 0..63
  const int sc = ((tid & 7) * 16) ^ ((sr & 7) * 16);
  const char* gA0 = (const char*)Abf + (size_t)(bm + sr) * 2048 + sc;
  const char* gA1 = gA0 + (size_t)64 * 2048;
  const char* gB0 = (const char*)Bt  + (size_t)(bn + sr) * 2048 + sc;
  const char* gB1 = gB0 + (size_t)64 * 2048;
  const int wbase = wv * 1024;

#define OSTAGE(tt) do { \
    char* s_ = lds[(tt) & 3]; \
    async16(gA0 + (tt) * 128, s_ + wbase); \
    async16(gA1 + (tt) * 128, s_ + 8192 + wbase); \
    async16(gB0 + (tt) * 128, s_ + 16384 + wbase); \
    async16(gB1 + (tt) * 128, s_ + 24576 + wbase); \
  } while (0)

  int aoff[2], boff[2];
#pragma unroll
  for (int ks = 0; ks < 2; ++ks) {
    const int c = ks * 64 + quad * 16;
    const int s = (l16 & 7) * 16;
    aoff[ks] = (wm * 64 + l16) * 128 + (c ^ s);
    boff[ks] = 16384 + (wn * 32 + l16) * 128 + (c ^ s);
  }

  floatx4 facc[4][2];
#pragma unroll
  for (int mi = 0; mi < 4; ++mi)
#pragma unroll
    for (int ni = 0; ni < 2; ++ni) { floatx4 zz = {0.f,0.f,0.f,0.f}; facc[mi][ni] = zz; }

  OSTAGE(0); OSTAGE(1); OSTAGE(2);
  VMCNT(8);
  __builtin_amdgcn_s_barrier();
  __builtin_amdgcn_sched_barrier(0);

#pragma unroll
  for (int t = 0; t < 16; ++t) {
    if (t + 3 < 16) OSTAGE(t + 3);

    const char* sl = lds[t & 3];
#pragma unroll
    for (int ks = 0; ks < 2; ++ks) {
      short8 af[4], bf[2];
#pragma unroll
      for (int mi = 0; mi < 4; ++mi)
        af[mi] = *(const short8*)(sl + aoff[ks] + mi * 2048);
#pragma unroll
      for (int ni = 0; ni < 2; ++ni)
        bf[ni] = *(const short8*)(sl + boff[ks] + ni * 2048);

      __builtin_amdgcn_s_setprio(1);
#pragma unroll
      for (int mi = 0; mi < 4; ++mi)
#pragma unroll
        for (int ni = 0; ni < 2; ++ni)
          facc[mi][ni] = __builtin_amdgcn_mfma_f32_16x16x32_bf16(
              af[mi], bf[ni], facc[mi][ni], 0, 0, 0);
      __builtin_amdgcn_s_setprio(0);
    }

    if (t < 15) {
      if (t <= 12)      VMCNT(8);
      else if (t == 13) VMCNT(4);
      else              VMCNT(0);
      __builtin_amdgcn_s_barrier();
      __builtin_amdgcn_sched_barrier(0);
    }
  }
#undef OSTAGE

  const int r0 = bm + wm * 64 + quad * 4;
  const int c0 = bn + wn * 32 + l16;
#pragma unroll
  for (int mi = 0; mi < 4; ++mi)
#pragma unroll
    for (int ni = 0; ni < 2; ++ni) {
      const int col = c0 + ni * 16;
      const float bb = bo[col];
#pragma unroll
      for (int r = 0; r < 4; ++r) {
        const int row = r0 + mi * 16 + r;
        const size_t idx = (size_t)row * EDIM + col;
        out[idx] = residual[idx] + facc[mi][ni][r] + bb;
      }
    }
}

// ---------------------------------------------------------------------------
// MFMA attention (bf16 Q/K/V); writes bf16 output rows directly (unchanged).
// ---------------------------------------------------------------------------
#define VT_LD 80
#define PB_LD 40

__global__ __launch_bounds__(256) void attn_mfma(
    const short* __restrict__ Q, const short* __restrict__ K,
    const short* __restrict__ V, short* __restrict__ Obf)
{
  const int tid  = threadIdx.x;
  const int lane = tid & 63;
  const int wave = tid >> 6;
  const int quad = lane >> 4;
  const int l16  = lane & 15;

  const int bh = blockIdx.y;
  const int h  = bh & (NHEAD - 1);
  const int b  = bh >> 4;
  const int s_blk = blockIdx.x * 64;
  const int col0  = h * DHEAD;

  __shared__ __align__(16) short VT[64 * VT_LD];
  __shared__ __align__(16) short Pb[4][16 * PB_LD];

  for (int task = tid; task < 320; task += 256) {
    const int kp  = task >> 3;
    const int dg  = task & 7;
    const int kk0 = kp * 2;
    int sA = s_blk - 15 + kk0;
    int sB = sA + 1;
    if (sA < 0) sA += SLEN;  if (sA >= SLEN) sA -= SLEN;
    if (sB < 0) sB += SLEN;  if (sB >= SLEN) sB -= SLEN;
    const short8 vA = *(const short8*)(V + (size_t)(sA * BSZ + b) * EDIM + col0 + dg * 8);
    const short8 vB = *(const short8*)(V + (size_t)(sB * BSZ + b) * EDIM + col0 + dg * 8);
#pragma unroll
    for (int j = 0; j < 8; ++j) {
      const int d = dg * 8 + j;
      const uint32_t pack = (uint32_t)(uint16_t)vA[j] | ((uint32_t)(uint16_t)vB[j] << 16);
      *(uint32_t*)&VT[d * VT_LD + kk0] = pack;
    }
  }

  const int sw = s_blk + wave * 16;
  short8 aq[2];
  {
    const size_t base = (size_t)((sw + l16) * BSZ + b) * EDIM + col0 + quad * 8;
    aq[0] = *(const short8*)(Q + base);
    aq[1] = *(const short8*)(Q + base + 32);
  }
  short8 bkf[2][2];
#pragma unroll
  for (int T = 0; T < 2; ++T) {
    int ks = sw - 15 + T * 16 + l16;
    if (ks < 0) ks += SLEN;
    if (ks >= SLEN) ks -= SLEN;
    const size_t base = (size_t)(ks * BSZ + b) * EDIM + col0 + quad * 8;
    bkf[T][0] = *(const short8*)(K + base);
    bkf[T][1] = *(const short8*)(K + base + 32);
  }

  floatx4 S[2];
  { floatx4 zz = {0.f, 0.f, 0.f, 0.f}; S[0] = zz; S[1] = zz; }
#pragma unroll
  for (int T = 0; T < 2; ++T) {
    S[T] = __builtin_amdgcn_mfma_f32_16x16x32_bf16(aq[0], bkf[T][0], S[T], 0, 0, 0);
    S[T] = __builtin_amdgcn_mfma_f32_16x16x32_bf16(aq[1], bkf[T][1], S[T], 0, 0, 0);
  }

  float sc[2][4];
#pragma unroll
  for (int T = 0; T < 2; ++T)
#pragma unroll
    for (int r = 0; r < 4; ++r) {
      const int m = quad * 4 + r;
      const int c = T * 16 + l16;
      const int d = c - m;
      sc[T][r] = (d >= 0 && d <= 15) ? S[T][r] * 0.125f : -1e30f;
    }
  float mx[4], sm[4];
#pragma unroll
  for (int r = 0; r < 4; ++r) mx[r] = fmaxf(sc[0][r], sc[1][r]);
#pragma unroll
  for (int off = 1; off <= 8; off <<= 1)
#pragma unroll
    for (int r = 0; r < 4; ++r) mx[r] = fmaxf(mx[r], __shfl_xor(mx[r], off));
  float p[2][4];
#pragma unroll
  for (int r = 0; r < 4; ++r) {
    p[0][r] = __expf(sc[0][r] - mx[r]);
    p[1][r] = __expf(sc[1][r] - mx[r]);
    sm[r] = p[0][r] + p[1][r];
  }
#pragma unroll
  for (int off = 1; off <= 8; off <<= 1)
#pragma unroll
    for (int r = 0; r < 4; ++r) sm[r] += __shfl_xor(sm[r], off);

  __syncthreads();

  short* Pw = Pb[wave];
#pragma unroll
  for (int T = 0; T < 2; ++T)
#pragma unroll
    for (int r = 0; r < 4; ++r) {
      const int m = quad * 4 + r;
      const int c = T * 16 + l16;
      Pw[m * PB_LD + c] = f2bf(p[T][r]);
    }
  __syncthreads();
  const short8 ap = *(const short8*)(Pw + l16 * PB_LD + quad * 8);

  floatx4 Oacc[4];
  { floatx4 zz = {0.f, 0.f, 0.f, 0.f}; Oacc[0] = zz; Oacc[1] = zz; Oacc[2] = zz; Oacc[3] = zz; }
#pragma unroll
  for (int nt = 0; nt < 4; ++nt) {
    const short8 bv = *(const short8*)(VT + (nt * 16 + l16) * VT_LD + wave * 16 + quad * 8);
    Oacc[nt] = __builtin_amdgcn_mfma_f32_16x16x32_bf16(ap, bv, Oacc[nt], 0, 0, 0);
  }

  float ism[4];
#pragma unroll
  for (int r = 0; r < 4; ++r) ism[r] = 1.0f / sm[r];
#pragma unroll
  for (int nt = 0; nt < 4; ++nt)
#pragma unroll
    for (int r = 0; r < 4; ++r) {
      const int m = quad * 4 + r;
      const int row = (sw + m) * BSZ + b;
      Obf[(size_t)row * EDIM + col0 + nt * 16 + l16] = f2bf(Oacc[nt][r] * ism[r]);
    }
}

// ---------------------------------------------------------------------------
extern "C" void kernel_launch(void* const* d_in, const int* in_sizes, int n_in,
                              void* d_out, int out_size, void* d_ws, size_t ws_size,
                              hipStream_t stream) {
  const float* x    = (const float*)d_in[0];
  const float* ln_g = (const float*)d_in[1];
  const float* ln_b = (const float*)d_in[2];
  const float* Wq   = (const float*)d_in[3];
  const float* bq   = (const float*)d_in[4];
  const float* Wk   = (const float*)d_in[5];
  const float* bk   = (const float*)d_in[6];
  const float* Wv   = (const float*)d_in[7];
  const float* bv   = (const float*)d_in[8];
  const float* Wo   = (const float*)d_in[9];
  const float* bo   = (const float*)d_in[10];
  float* out = (float*)d_out;

  char* ws = (char*)d_ws;
  char*  xn_i8   = ws;                                      // 4 MB (dead after qkv)
  short* Wt      = (short*)(ws + ((size_t)4  << 20));       // 8 MB (z3 live to gemm_o)
  char*  w_i8    = ws + ((size_t)12 << 20);                 // 3 MB
  short* QKV     = (short*)(ws + ((size_t)16 << 20));       // 24 MB
  float* xn_scl  = (float*)(ws + ((size_t)44 << 20));       // 16 KB
  float* w_scl   = (float*)(ws + ((size_t)44 << 20) + (1 << 16));
  short* Obf     = (short*)ws;   // 8 MB, overlays xn_i8 + Wt z0/z1 (dead by attn)

  prep_kernel<<<NTOK + 1024, 256, 0, stream>>>(x, ln_g, ln_b, xn_i8, xn_scl,
                                               Wq, Wk, Wv, Wo, Wt);
  quant_w<<<3 * EDIM, 256, 0, stream>>>(Wt, w_i8, w_scl);
  gemm_qkv256<<<192, 512, 0, stream>>>(xn_i8, xn_scl, w_i8, w_scl,
                                       bq, bk, bv, QKV);
  attn_mfma<<<dim3(SLEN / 64, BSZ * NHEAD), 256, 0, stream>>>(
      QKV, QKV + (size_t)NTOK * EDIM, QKV + (size_t)2 * NTOK * EDIM, Obf);
  gemm_o128<<<256, 512, 0, stream>>>(
      Obf, Wt + (size_t)3 * EDIM * EDIM, bo, x, out);
}

// Round 9
// 147.947 us; speedup vs baseline: 1.0861x; 1.0156x over previous
//
#include <hip/hip_runtime.h>
#include <cstdint>
#include <cstddef>

// Problem constants (fixed by reference)
#define SLEN 2048
#define BSZ  2
#define EDIM 1024
#define NHEAD 16
#define DHEAD 64
#define NTOK (SLEN*BSZ)   // 4096

typedef __attribute__((ext_vector_type(8))) short short8;   // 8 x bf16 bits
typedef __attribute__((ext_vector_type(4))) float floatx4;
typedef __attribute__((ext_vector_type(4))) int   int4v;

__device__ __forceinline__ short f2bf(float f) {
  union { float f; uint32_t u; } v; v.f = f;
  uint32_t r = v.u + 0x7fffu + ((v.u >> 16) & 1u);   // round-nearest-even
  return (short)(r >> 16);
}
__device__ __forceinline__ float bf2f(short s) {
  union { uint32_t u; float f; } v; v.u = ((uint32_t)(uint16_t)s) << 16;
  return v.f;
}
__device__ __forceinline__ int q8(float f, float inv) {
  int q = __float2int_rn(f * inv);
  return min(127, max(-127, q));
}
__device__ __forceinline__ void async16(const void* g, void* l) {
  __builtin_amdgcn_global_load_lds((const __attribute__((address_space(1))) void*)g,
                                   (__attribute__((address_space(3))) void*)l,
                                   16, 0, 0);
}
#define VMCNT(n) asm volatile("s_waitcnt vmcnt(" #n ")" ::: "memory")

// ---------------------------------------------------------------------------
// prep: blocks [0,1024): 64x64 weight transpose tiles -> Wt bf16  (HEAD of
//       grid — critical-path producer for quant_w/gemm_qkv starts first).
//       blocks [1024, 1024+NTOK): LayerNorm rows -> int8 + per-row scale.
// ROUND 8: W-blocks moved to grid head (tail-imbalance fix; R6/R7 evidence).
// ---------------------------------------------------------------------------
__global__ __launch_bounds__(256) void prep_kernel(
    const float* __restrict__ x, const float* __restrict__ g,
    const float* __restrict__ b, char* __restrict__ xn_i8,
    float* __restrict__ xn_scl,
    const float* __restrict__ W0, const float* __restrict__ W1,
    const float* __restrict__ W2, const float* __restrict__ W3,
    short* __restrict__ Wt_base)
{
  const int bid = blockIdx.x;
  const int tid = threadIdx.x;

  if (bid >= 1024) {
    // ---- LayerNorm row ----
    const int row = bid - 1024;
    const float4 v = ((const float4*)(x + (size_t)row * EDIM))[tid];
    float s  = v.x + v.y + v.z + v.w;
    float ss = v.x * v.x + v.y * v.y + v.z * v.z + v.w * v.w;
#pragma unroll
    for (int off = 32; off; off >>= 1) {
      s  += __shfl_xor(s, off);
      ss += __shfl_xor(ss, off);
    }
    __shared__ float ws_s[4], ws_ss[4], ws_m[4];
    const int lane = tid & 63, wave = tid >> 6;
    if (lane == 0) { ws_s[wave] = s; ws_ss[wave] = ss; }
    __syncthreads();
    s  = ws_s[0] + ws_s[1] + ws_s[2] + ws_s[3];
    ss = ws_ss[0] + ws_ss[1] + ws_ss[2] + ws_ss[3];

    const float mean = s * (1.0f / EDIM);
    const float var  = ss * (1.0f / EDIM) - mean * mean;
    const float rs   = rsqrtf(var + 1e-5f);

    const float4 gv = ((const float4*)g)[tid];
    const float4 bv = ((const float4*)b)[tid];
    const float n0 = (v.x - mean) * rs * gv.x + bv.x;
    const float n1 = (v.y - mean) * rs * gv.y + bv.y;
    const float n2 = (v.z - mean) * rs * gv.z + bv.z;
    const float n3 = (v.w - mean) * rs * gv.w + bv.w;

    float am = fmaxf(fmaxf(fabsf(n0), fabsf(n1)), fmaxf(fabsf(n2), fabsf(n3)));
#pragma unroll
    for (int off = 32; off; off >>= 1) am = fmaxf(am, __shfl_xor(am, off));
    if (lane == 0) ws_m[wave] = am;
    __syncthreads();
    am = fmaxf(fmaxf(ws_m[0], ws_m[1]), fmaxf(ws_m[2], ws_m[3]));

    const float inv = (am > 1e-30f) ? 127.0f / am : 0.0f;
    const int q0 = q8(n0, inv), q1 = q8(n1, inv), q2 = q8(n2, inv), q3 = q8(n3, inv);
    const uint32_t pack = (uint32_t)(q0 & 0xff) | ((uint32_t)(q1 & 0xff) << 8) |
                          ((uint32_t)(q2 & 0xff) << 16) | ((uint32_t)(q3 & 0xff) << 24);
    ((uint32_t*)(xn_i8 + (size_t)row * EDIM))[tid] = pack;
    if (tid == 0) xn_scl[row] = am * (1.0f / 127.0f);
  } else {
    // ---- 64x64 transpose tile (grid head) ----
    const int t   = bid;                 // 0..1023
    const int z   = t >> 8;              // 0..3
    const int rem = t & 255;
    const int n0  = (rem & 15) * 64;
    const int k0  = (rem >> 4) * 64;
    const float* W = (z == 0) ? W0 : (z == 1) ? W1 : (z == 2) ? W2 : W3;
    short* Wt = Wt_base + (size_t)z * EDIM * EDIM;

    __shared__ float tile[64][65];       // pad 65: 2-way bank alias (free)
    const int tx = tid & 15;
    const int ty = tid >> 4;             // 0..15
#pragma unroll
    for (int i = 0; i < 4; ++i) {
      const float4 v = *(const float4*)(W + (size_t)(k0 + ty + 16 * i) * EDIM + n0 + tx * 4);
      float* d = &tile[ty + 16 * i][tx * 4];
      d[0] = v.x; d[1] = v.y; d[2] = v.z; d[3] = v.w;
    }
    __syncthreads();
#pragma unroll
    for (int i = 0; i < 4; ++i) {
      short4 s4;
      s4.x = f2bf(tile[tx * 4 + 0][ty + 16 * i]);
      s4.y = f2bf(tile[tx * 4 + 1][ty + 16 * i]);
      s4.z = f2bf(tile[tx * 4 + 2][ty + 16 * i]);
      s4.w = f2bf(tile[tx * 4 + 3][ty + 16 * i]);
      *(short4*)(Wt + (size_t)(n0 + ty + 16 * i) * EDIM + k0 + tx * 4) = s4;
    }
  }
}

// ---------------------------------------------------------------------------
// quant_w: one block per Wt row R (Q,K,V matrices only; Wo stays bf16):
// bf16 -> int8 + per-row (= per output column) scale.
// ---------------------------------------------------------------------------
__global__ __launch_bounds__(256) void quant_w(
    const short* __restrict__ Wt, char* __restrict__ w_i8,
    float* __restrict__ w_scl)
{
  const int R = blockIdx.x;      // 0..3071
  const int tid = threadIdx.x;
  const short4 s4 = ((const short4*)(Wt + (size_t)R * EDIM))[tid];
  const float w0 = bf2f(s4.x), w1 = bf2f(s4.y), w2 = bf2f(s4.z), w3 = bf2f(s4.w);

  float am = fmaxf(fmaxf(fabsf(w0), fabsf(w1)), fmaxf(fabsf(w2), fabsf(w3)));
#pragma unroll
  for (int off = 32; off; off >>= 1) am = fmaxf(am, __shfl_xor(am, off));
  __shared__ float wm[4];
  const int lane = tid & 63, wave = tid >> 6;
  if (lane == 0) wm[wave] = am;
  __syncthreads();
  am = fmaxf(fmaxf(wm[0], wm[1]), fmaxf(wm[2], wm[3]));

  const float inv = (am > 1e-30f) ? 127.0f / am : 0.0f;
  const int q0 = q8(w0, inv), q1 = q8(w1, inv), q2 = q8(w2, inv), q3 = q8(w3, inv);
  const uint32_t pack = (uint32_t)(q0 & 0xff) | ((uint32_t)(q1 & 0xff) << 8) |
                        ((uint32_t)(q2 & 0xff) << 16) | ((uint32_t)(q3 & 0xff) << 24);
  ((uint32_t*)(w_i8 + (size_t)R * EDIM))[tid] = pack;
  if (tid == 0) w_scl[R] = am * (1.0f / 127.0f);
}

// ---------------------------------------------------------------------------
// QKV projection, W8A8 int8, 256x256 tile, ring-of-4 K-tile pipeline.
// (unchanged — validated, absmax canary held across 7 rounds)
// ---------------------------------------------------------------------------
__global__ __launch_bounds__(512, 2) void gemm_qkv256(
    const char* __restrict__ xn_i8, const float* __restrict__ xn_scl,
    const char* __restrict__ w_i8, const float* __restrict__ w_scl,
    const float* __restrict__ bq, const float* __restrict__ bk,
    const float* __restrict__ bv, short* __restrict__ qkv_base)
{
  __shared__ __align__(16) char lds[4][32768];   // 128 KiB ring

  const int bid = blockIdx.x;                    // 0..191
  const int lin = (bid & 7) * 24 + (bid >> 3);
  const int mt  = lin & 15;
  const int nt  = lin >> 4;
  const int z   = nt >> 2;
  const int bm  = mt * 256;
  const int bnz = (nt & 3) * 256;

  const float* bias = (z == 0) ? bq : (z == 1) ? bk : bv;
  short* out = qkv_base + (size_t)z * NTOK * EDIM;

  const int tid = threadIdx.x;
  const int wv  = tid >> 6;
  const int ln  = tid & 63;
  const int q   = ln >> 4;
  const int l16 = ln & 15;
  const int wm  = wv >> 2;
  const int wn  = wv & 3;

  const int sr = tid >> 2;
  const int sc = ((tid & 3) * 16) ^ ((sr & 3) * 16);
  const char* gA0 = xn_i8 + (size_t)(bm + sr) * EDIM + sc;
  const char* gA1 = gA0 + (size_t)128 * EDIM;
  const char* gB0 = w_i8 + ((size_t)z << 20) + (size_t)(bnz + sr) * EDIM + sc;
  const char* gB1 = gB0 + (size_t)128 * EDIM;
  const int wbase = wv * 1024;

#define QSTAGE(tt) do { \
    char* s_ = lds[(tt) & 3]; \
    async16(gA0 + (tt) * 64, s_ + wbase); \
    async16(gA1 + (tt) * 64, s_ + 8192 + wbase); \
    async16(gB0 + (tt) * 64, s_ + 16384 + wbase); \
    async16(gB1 + (tt) * 64, s_ + 24576 + wbase); \
  } while (0)

  const int swz  = (q * 16) ^ ((l16 & 3) * 16);
  const int aoff = (wm * 128 + l16) * 64 + swz;
  const int boff = 16384 + (wn * 64 + l16) * 64 + swz;

  int4v acc[8][4];
#pragma unroll
  for (int mi = 0; mi < 8; ++mi)
#pragma unroll
    for (int ni = 0; ni < 4; ++ni) { int4v zz = {0,0,0,0}; acc[mi][ni] = zz; }

  QSTAGE(0); QSTAGE(1); QSTAGE(2);
  VMCNT(8);
  __builtin_amdgcn_s_barrier();
  __builtin_amdgcn_sched_barrier(0);

#pragma unroll
  for (int t = 0; t < 16; ++t) {
    if (t + 3 < 16) QSTAGE(t + 3);

    const char* sl = lds[t & 3];
    int4v bf[4], af[8];
#pragma unroll
    for (int ni = 0; ni < 4; ++ni)
      bf[ni] = *(const int4v*)(sl + boff + ni * 1024);
#pragma unroll
    for (int mi = 0; mi < 8; ++mi)
      af[mi] = *(const int4v*)(sl + aoff + mi * 1024);

    __builtin_amdgcn_s_setprio(1);
#pragma unroll
    for (int mi = 0; mi < 8; ++mi)
#pragma unroll
      for (int ni = 0; ni < 4; ++ni)
        acc[mi][ni] = __builtin_amdgcn_mfma_i32_16x16x64_i8(
            af[mi], bf[ni], acc[mi][ni], 0, 0, 0);
    __builtin_amdgcn_s_setprio(0);

    if (t < 15) {
      if (t <= 12)      VMCNT(8);
      else if (t == 13) VMCNT(4);
      else              VMCNT(0);
      __builtin_amdgcn_s_barrier();
      __builtin_amdgcn_sched_barrier(0);
    }
  }
#undef QSTAGE

  const int rbase = bm + wm * 128 + q * 4;
  const int cbl   = bnz + wn * 64 + l16;
#pragma unroll
  for (int mi = 0; mi < 8; ++mi) {
    float sa[4];
#pragma unroll
    for (int r = 0; r < 4; ++r) sa[r] = xn_scl[rbase + mi * 16 + r];
#pragma unroll
    for (int ni = 0; ni < 4; ++ni) {
      const int c  = cbl + ni * 16;
      const float sb = w_scl[z * EDIM + c];
      const float bb = bias[c];
      const int4v v = acc[mi][ni];
#pragma unroll
      for (int r = 0; r < 4; ++r)
        out[(size_t)(rbase + mi * 16 + r) * EDIM + c] =
            f2bf((float)v[r] * (sa[r] * sb) + bb);
    }
  }
}

// ---------------------------------------------------------------------------
// O projection, bf16 MFMA, 128x128 tile, ring-of-4 (round-4 version verbatim).
// ---------------------------------------------------------------------------
__global__ __launch_bounds__(512, 2) void gemm_o128(
    const short* __restrict__ Abf, const short* __restrict__ Bt,
    const float* __restrict__ bo, const float* __restrict__ residual,
    float* __restrict__ out)
{
  __shared__ __align__(16) char lds[4][32768];   // slot: A @0 (16K), B @16384 (16K)

  const int bid = blockIdx.x;
  const int lin = (bid & 7) * 32 + (bid >> 3);   // 0..255
  const int mt  = lin >> 3;                      // 0..31
  const int nt  = lin & 7;                       // 0..7
  const int bm  = mt * 128;
  const int bn  = nt * 128;

  const int tid = threadIdx.x;
  const int wv  = tid >> 6;
  const int ln  = tid & 63;
  const int quad = ln >> 4;
  const int l16  = ln & 15;
  const int wm  = wv >> 2;       // 0..1  (64-row half)
  const int wn  = wv & 3;        // 0..3  (32-col quarter)

  const int sr = tid >> 3;                         // 0..63
  const int sc = ((tid & 7) * 16) ^ ((sr & 7) * 16);
  const char* gA0 = (const char*)Abf + (size_t)(bm + sr) * 2048 + sc;
  const char* gA1 = gA0 + (size_t)64 * 2048;
  const char* gB0 = (const char*)Bt  + (size_t)(bn + sr) * 2048 + sc;
  const char* gB1 = gB0 + (size_t)64 * 2048;
  const int wbase = wv * 1024;

#define OSTAGE(tt) do { \
    char* s_ = lds[(tt) & 3]; \
    async16(gA0 + (tt) * 128, s_ + wbase); \
    async16(gA1 + (tt) * 128, s_ + 8192 + wbase); \
    async16(gB0 + (tt) * 128, s_ + 16384 + wbase); \
    async16(gB1 + (tt) * 128, s_ + 24576 + wbase); \
  } while (0)

  int aoff[2], boff[2];
#pragma unroll
  for (int ks = 0; ks < 2; ++ks) {
    const int c = ks * 64 + quad * 16;
    const int s = (l16 & 7) * 16;
    aoff[ks] = (wm * 64 + l16) * 128 + (c ^ s);
    boff[ks] = 16384 + (wn * 32 + l16) * 128 + (c ^ s);
  }

  floatx4 facc[4][2];
#pragma unroll
  for (int mi = 0; mi < 4; ++mi)
#pragma unroll
    for (int ni = 0; ni < 2; ++ni) { floatx4 zz = {0.f,0.f,0.f,0.f}; facc[mi][ni] = zz; }

  OSTAGE(0); OSTAGE(1); OSTAGE(2);
  VMCNT(8);
  __builtin_amdgcn_s_barrier();
  __builtin_amdgcn_sched_barrier(0);

#pragma unroll
  for (int t = 0; t < 16; ++t) {
    if (t + 3 < 16) OSTAGE(t + 3);

    const char* sl = lds[t & 3];
#pragma unroll
    for (int ks = 0; ks < 2; ++ks) {
      short8 af[4], bf[2];
#pragma unroll
      for (int mi = 0; mi < 4; ++mi)
        af[mi] = *(const short8*)(sl + aoff[ks] + mi * 2048);
#pragma unroll
      for (int ni = 0; ni < 2; ++ni)
        bf[ni] = *(const short8*)(sl + boff[ks] + ni * 2048);

      __builtin_amdgcn_s_setprio(1);
#pragma unroll
      for (int mi = 0; mi < 4; ++mi)
#pragma unroll
        for (int ni = 0; ni < 2; ++ni)
          facc[mi][ni] = __builtin_amdgcn_mfma_f32_16x16x32_bf16(
              af[mi], bf[ni], facc[mi][ni], 0, 0, 0);
      __builtin_amdgcn_s_setprio(0);
    }

    if (t < 15) {
      if (t <= 12)      VMCNT(8);
      else if (t == 13) VMCNT(4);
      else              VMCNT(0);
      __builtin_amdgcn_s_barrier();
      __builtin_amdgcn_sched_barrier(0);
    }
  }
#undef OSTAGE

  const int r0 = bm + wm * 64 + quad * 4;
  const int c0 = bn + wn * 32 + l16;
#pragma unroll
  for (int mi = 0; mi < 4; ++mi)
#pragma unroll
    for (int ni = 0; ni < 2; ++ni) {
      const int col = c0 + ni * 16;
      const float bb = bo[col];
#pragma unroll
      for (int r = 0; r < 4; ++r) {
        const int row = r0 + mi * 16 + r;
        const size_t idx = (size_t)row * EDIM + col;
        out[idx] = residual[idx] + facc[mi][ni][r] + bb;
      }
    }
}

// ---------------------------------------------------------------------------
// MFMA attention (bf16 Q/K/V); writes bf16 output rows directly (unchanged).
// ---------------------------------------------------------------------------
#define VT_LD 80
#define PB_LD 40

__global__ __launch_bounds__(256) void attn_mfma(
    const short* __restrict__ Q, const short* __restrict__ K,
    const short* __restrict__ V, short* __restrict__ Obf)
{
  const int tid  = threadIdx.x;
  const int lane = tid & 63;
  const int wave = tid >> 6;
  const int quad = lane >> 4;
  const int l16  = lane & 15;

  const int bh = blockIdx.y;
  const int h  = bh & (NHEAD - 1);
  const int b  = bh >> 4;
  const int s_blk = blockIdx.x * 64;
  const int col0  = h * DHEAD;

  __shared__ __align__(16) short VT[64 * VT_LD];
  __shared__ __align__(16) short Pb[4][16 * PB_LD];

  for (int task = tid; task < 320; task += 256) {
    const int kp  = task >> 3;
    const int dg  = task & 7;
    const int kk0 = kp * 2;
    int sA = s_blk - 15 + kk0;
    int sB = sA + 1;
    if (sA < 0) sA += SLEN;  if (sA >= SLEN) sA -= SLEN;
    if (sB < 0) sB += SLEN;  if (sB >= SLEN) sB -= SLEN;
    const short8 vA = *(const short8*)(V + (size_t)(sA * BSZ + b) * EDIM + col0 + dg * 8);
    const short8 vB = *(const short8*)(V + (size_t)(sB * BSZ + b) * EDIM + col0 + dg * 8);
#pragma unroll
    for (int j = 0; j < 8; ++j) {
      const int d = dg * 8 + j;
      const uint32_t pack = (uint32_t)(uint16_t)vA[j] | ((uint32_t)(uint16_t)vB[j] << 16);
      *(uint32_t*)&VT[d * VT_LD + kk0] = pack;
    }
  }

  const int sw = s_blk + wave * 16;
  short8 aq[2];
  {
    const size_t base = (size_t)((sw + l16) * BSZ + b) * EDIM + col0 + quad * 8;
    aq[0] = *(const short8*)(Q + base);
    aq[1] = *(const short8*)(Q + base + 32);
  }
  short8 bkf[2][2];
#pragma unroll
  for (int T = 0; T < 2; ++T) {
    int ks = sw - 15 + T * 16 + l16;
    if (ks < 0) ks += SLEN;
    if (ks >= SLEN) ks -= SLEN;
    const size_t base = (size_t)(ks * BSZ + b) * EDIM + col0 + quad * 8;
    bkf[T][0] = *(const short8*)(K + base);
    bkf[T][1] = *(const short8*)(K + base + 32);
  }

  floatx4 S[2];
  { floatx4 zz = {0.f, 0.f, 0.f, 0.f}; S[0] = zz; S[1] = zz; }
#pragma unroll
  for (int T = 0; T < 2; ++T) {
    S[T] = __builtin_amdgcn_mfma_f32_16x16x32_bf16(aq[0], bkf[T][0], S[T], 0, 0, 0);
    S[T] = __builtin_amdgcn_mfma_f32_16x16x32_bf16(aq[1], bkf[T][1], S[T], 0, 0, 0);
  }

  float sc[2][4];
#pragma unroll
  for (int T = 0; T < 2; ++T)
#pragma unroll
    for (int r = 0; r < 4; ++r) {
      const int m = quad * 4 + r;
      const int c = T * 16 + l16;
      const int d = c - m;
      sc[T][r] = (d >= 0 && d <= 15) ? S[T][r] * 0.125f : -1e30f;
    }
  float mx[4], sm[4];
#pragma unroll
  for (int r = 0; r < 4; ++r) mx[r] = fmaxf(sc[0][r], sc[1][r]);
#pragma unroll
  for (int off = 1; off <= 8; off <<= 1)
#pragma unroll
    for (int r = 0; r < 4; ++r) mx[r] = fmaxf(mx[r], __shfl_xor(mx[r], off));
  float p[2][4];
#pragma unroll
  for (int r = 0; r < 4; ++r) {
    p[0][r] = __expf(sc[0][r] - mx[r]);
    p[1][r] = __expf(sc[1][r] - mx[r]);
    sm[r] = p[0][r] + p[1][r];
  }
#pragma unroll
  for (int off = 1; off <= 8; off <<= 1)
#pragma unroll
    for (int r = 0; r < 4; ++r) sm[r] += __shfl_xor(sm[r], off);

  __syncthreads();

  short* Pw = Pb[wave];
#pragma unroll
  for (int T = 0; T < 2; ++T)
#pragma unroll
    for (int r = 0; r < 4; ++r) {
      const int m = quad * 4 + r;
      const int c = T * 16 + l16;
      Pw[m * PB_LD + c] = f2bf(p[T][r]);
    }
  __syncthreads();
  const short8 ap = *(const short8*)(Pw + l16 * PB_LD + quad * 8);

  floatx4 Oacc[4];
  { floatx4 zz = {0.f, 0.f, 0.f, 0.f}; Oacc[0] = zz; Oacc[1] = zz; Oacc[2] = zz; Oacc[3] = zz; }
#pragma unroll
  for (int nt = 0; nt < 4; ++nt) {
    const short8 bv = *(const short8*)(VT + (nt * 16 + l16) * VT_LD + wave * 16 + quad * 8);
    Oacc[nt] = __builtin_amdgcn_mfma_f32_16x16x32_bf16(ap, bv, Oacc[nt], 0, 0, 0);
  }

  float ism[4];
#pragma unroll
  for (int r = 0; r < 4; ++r) ism[r] = 1.0f / sm[r];
#pragma unroll
  for (int nt = 0; nt < 4; ++nt)
#pragma unroll
    for (int r = 0; r < 4; ++r) {
      const int m = quad * 4 + r;
      const int row = (sw + m) * BSZ + b;
      Obf[(size_t)row * EDIM + col0 + nt * 16 + l16] = f2bf(Oacc[nt][r] * ism[r]);
    }
}

// ---------------------------------------------------------------------------
extern "C" void kernel_launch(void* const* d_in, const int* in_sizes, int n_in,
                              void* d_out, int out_size, void* d_ws, size_t ws_size,
                              hipStream_t stream) {
  const float* x    = (const float*)d_in[0];
  const float* ln_g = (const float*)d_in[1];
  const float* ln_b = (const float*)d_in[2];
  const float* Wq   = (const float*)d_in[3];
  const float* bq   = (const float*)d_in[4];
  const float* Wk   = (const float*)d_in[5];
  const float* bk   = (const float*)d_in[6];
  const float* Wv   = (const float*)d_in[7];
  const float* bv   = (const float*)d_in[8];
  const float* Wo   = (const float*)d_in[9];
  const float* bo   = (const float*)d_in[10];
  float* out = (float*)d_out;

  char* ws = (char*)d_ws;
  char*  xn_i8   = ws;                                      // 4 MB (dead after qkv)
  short* Wt      = (short*)(ws + ((size_t)4  << 20));       // 8 MB (z3 live to gemm_o)
  char*  w_i8    = ws + ((size_t)12 << 20);                 // 3 MB
  short* QKV     = (short*)(ws + ((size_t)16 << 20));       // 24 MB
  float* xn_scl  = (float*)(ws + ((size_t)44 << 20));       // 16 KB
  float* w_scl   = (float*)(ws + ((size_t)44 << 20) + (1 << 16));
  short* Obf     = (short*)ws;   // 8 MB, overlays xn_i8 + Wt z0/z1 (dead by attn)

  prep_kernel<<<NTOK + 1024, 256, 0, stream>>>(x, ln_g, ln_b, xn_i8, xn_scl,
                                               Wq, Wk, Wv, Wo, Wt);
  quant_w<<<3 * EDIM, 256, 0, stream>>>(Wt, w_i8, w_scl);
  gemm_qkv256<<<192, 512, 0, stream>>>(xn_i8, xn_scl, w_i8, w_scl,
                                       bq, bk, bv, QKV);
  attn_mfma<<<dim3(SLEN / 64, BSZ * NHEAD), 256, 0, stream>>>(
      QKV, QKV + (size_t)NTOK * EDIM, QKV + (size_t)2 * NTOK * EDIM, Obf);
  gemm_o128<<<256, 512, 0, stream>>>(
      Obf, Wt + (size_t)3 * EDIM * EDIM, bo, x, out);
}

// Round 10
// 145.622 us; speedup vs baseline: 1.1035x; 1.0160x over previous
//
#include <hip/hip_runtime.h>
#include <cstdint>
#include <cstddef>

// Problem constants (fixed by reference)
#define SLEN 2048
#define BSZ  2
#define EDIM 1024
#define NHEAD 16
#define DHEAD 64
#define NTOK (SLEN*BSZ)   // 4096

typedef __attribute__((ext_vector_type(8))) short short8;   // 8 x bf16 bits
typedef __attribute__((ext_vector_type(4))) float floatx4;
typedef __attribute__((ext_vector_type(4))) int   int4v;

__device__ __forceinline__ short f2bf(float f) {
  union { float f; uint32_t u; } v; v.f = f;
  uint32_t r = v.u + 0x7fffu + ((v.u >> 16) & 1u);   // round-nearest-even
  return (short)(r >> 16);
}
__device__ __forceinline__ float bf2f(short s) {
  union { uint32_t u; float f; } v; v.u = ((uint32_t)(uint16_t)s) << 16;
  return v.f;
}
__device__ __forceinline__ int q8(float f, float inv) {
  int q = __float2int_rn(f * inv);
  return min(127, max(-127, q));
}
__device__ __forceinline__ void async16(const void* g, void* l) {
  __builtin_amdgcn_global_load_lds((const __attribute__((address_space(1))) void*)g,
                                   (__attribute__((address_space(3))) void*)l,
                                   16, 0, 0);
}
#define VMCNT(n) asm volatile("s_waitcnt vmcnt(" #n ")" ::: "memory")

// ---------------------------------------------------------------------------
// prep: blocks [0,1024): 64x64 weight transpose tiles -> Wt bf16  (HEAD of
//       grid — critical-path producer for quant_w/gemm_qkv starts first).
//       blocks [1024, 1024+NTOK): LayerNorm rows -> int8 + per-row scale.
// (R8 version — validated best)
// ---------------------------------------------------------------------------
__global__ __launch_bounds__(256) void prep_kernel(
    const float* __restrict__ x, const float* __restrict__ g,
    const float* __restrict__ b, char* __restrict__ xn_i8,
    float* __restrict__ xn_scl,
    const float* __restrict__ W0, const float* __restrict__ W1,
    const float* __restrict__ W2, const float* __restrict__ W3,
    short* __restrict__ Wt_base)
{
  const int bid = blockIdx.x;
  const int tid = threadIdx.x;

  if (bid >= 1024) {
    // ---- LayerNorm row ----
    const int row = bid - 1024;
    const float4 v = ((const float4*)(x + (size_t)row * EDIM))[tid];
    float s  = v.x + v.y + v.z + v.w;
    float ss = v.x * v.x + v.y * v.y + v.z * v.z + v.w * v.w;
#pragma unroll
    for (int off = 32; off; off >>= 1) {
      s  += __shfl_xor(s, off);
      ss += __shfl_xor(ss, off);
    }
    __shared__ float ws_s[4], ws_ss[4], ws_m[4];
    const int lane = tid & 63, wave = tid >> 6;
    if (lane == 0) { ws_s[wave] = s; ws_ss[wave] = ss; }
    __syncthreads();
    s  = ws_s[0] + ws_s[1] + ws_s[2] + ws_s[3];
    ss = ws_ss[0] + ws_ss[1] + ws_ss[2] + ws_ss[3];

    const float mean = s * (1.0f / EDIM);
    const float var  = ss * (1.0f / EDIM) - mean * mean;
    const float rs   = rsqrtf(var + 1e-5f);

    const float4 gv = ((const float4*)g)[tid];
    const float4 bv = ((const float4*)b)[tid];
    const float n0 = (v.x - mean) * rs * gv.x + bv.x;
    const float n1 = (v.y - mean) * rs * gv.y + bv.y;
    const float n2 = (v.z - mean) * rs * gv.z + bv.z;
    const float n3 = (v.w - mean) * rs * gv.w + bv.w;

    float am = fmaxf(fmaxf(fabsf(n0), fabsf(n1)), fmaxf(fabsf(n2), fabsf(n3)));
#pragma unroll
    for (int off = 32; off; off >>= 1) am = fmaxf(am, __shfl_xor(am, off));
    if (lane == 0) ws_m[wave] = am;
    __syncthreads();
    am = fmaxf(fmaxf(ws_m[0], ws_m[1]), fmaxf(ws_m[2], ws_m[3]));

    const float inv = (am > 1e-30f) ? 127.0f / am : 0.0f;
    const int q0 = q8(n0, inv), q1 = q8(n1, inv), q2 = q8(n2, inv), q3 = q8(n3, inv);
    const uint32_t pack = (uint32_t)(q0 & 0xff) | ((uint32_t)(q1 & 0xff) << 8) |
                          ((uint32_t)(q2 & 0xff) << 16) | ((uint32_t)(q3 & 0xff) << 24);
    ((uint32_t*)(xn_i8 + (size_t)row * EDIM))[tid] = pack;
    if (tid == 0) xn_scl[row] = am * (1.0f / 127.0f);
  } else {
    // ---- 64x64 transpose tile (grid head) ----
    const int t   = bid;                 // 0..1023
    const int z   = t >> 8;              // 0..3
    const int rem = t & 255;
    const int n0  = (rem & 15) * 64;
    const int k0  = (rem >> 4) * 64;
    const float* W = (z == 0) ? W0 : (z == 1) ? W1 : (z == 2) ? W2 : W3;
    short* Wt = Wt_base + (size_t)z * EDIM * EDIM;

    __shared__ float tile[64][65];       // pad 65: 2-way bank alias (free)
    const int tx = tid & 15;
    const int ty = tid >> 4;             // 0..15
#pragma unroll
    for (int i = 0; i < 4; ++i) {
      const float4 v = *(const float4*)(W + (size_t)(k0 + ty + 16 * i) * EDIM + n0 + tx * 4);
      float* d = &tile[ty + 16 * i][tx * 4];
      d[0] = v.x; d[1] = v.y; d[2] = v.z; d[3] = v.w;
    }
    __syncthreads();
#pragma unroll
    for (int i = 0; i < 4; ++i) {
      short4 s4;
      s4.x = f2bf(tile[tx * 4 + 0][ty + 16 * i]);
      s4.y = f2bf(tile[tx * 4 + 1][ty + 16 * i]);
      s4.z = f2bf(tile[tx * 4 + 2][ty + 16 * i]);
      s4.w = f2bf(tile[tx * 4 + 3][ty + 16 * i]);
      *(short4*)(Wt + (size_t)(n0 + ty + 16 * i) * EDIM + k0 + tx * 4) = s4;
    }
  }
}

// ---------------------------------------------------------------------------
// quant_w: one block per Wt row R (Q,K,V matrices only; Wo stays bf16):
// bf16 -> int8 + per-row (= per output column) scale.
// ---------------------------------------------------------------------------
__global__ __launch_bounds__(256) void quant_w(
    const short* __restrict__ Wt, char* __restrict__ w_i8,
    float* __restrict__ w_scl)
{
  const int R = blockIdx.x;      // 0..3071
  const int tid = threadIdx.x;
  const short4 s4 = ((const short4*)(Wt + (size_t)R * EDIM))[tid];
  const float w0 = bf2f(s4.x), w1 = bf2f(s4.y), w2 = bf2f(s4.z), w3 = bf2f(s4.w);

  float am = fmaxf(fmaxf(fabsf(w0), fabsf(w1)), fmaxf(fabsf(w2), fabsf(w3)));
#pragma unroll
  for (int off = 32; off; off >>= 1) am = fmaxf(am, __shfl_xor(am, off));
  __shared__ float wm[4];
  const int lane = tid & 63, wave = tid >> 6;
  if (lane == 0) wm[wave] = am;
  __syncthreads();
  am = fmaxf(fmaxf(wm[0], wm[1]), fmaxf(wm[2], wm[3]));

  const float inv = (am > 1e-30f) ? 127.0f / am : 0.0f;
  const int q0 = q8(w0, inv), q1 = q8(w1, inv), q2 = q8(w2, inv), q3 = q8(w3, inv);
  const uint32_t pack = (uint32_t)(q0 & 0xff) | ((uint32_t)(q1 & 0xff) << 8) |
                        ((uint32_t)(q2 & 0xff) << 16) | ((uint32_t)(q3 & 0xff) << 24);
  ((uint32_t*)(w_i8 + (size_t)R * EDIM))[tid] = pack;
  if (tid == 0) w_scl[R] = am * (1.0f / 127.0f);
}

// ---------------------------------------------------------------------------
// QKV projection, W8A8 int8, 256x256 tile, ring-of-4 K-tile pipeline.
// (unchanged — validated, absmax canary held across 8 rounds)
// ---------------------------------------------------------------------------
__global__ __launch_bounds__(512, 2) void gemm_qkv256(
    const char* __restrict__ xn_i8, const float* __restrict__ xn_scl,
    const char* __restrict__ w_i8, const float* __restrict__ w_scl,
    const float* __restrict__ bq, const float* __restrict__ bk,
    const float* __restrict__ bv, short* __restrict__ qkv_base)
{
  __shared__ __align__(16) char lds[4][32768];   // 128 KiB ring

  const int bid = blockIdx.x;                    // 0..191
  const int lin = (bid & 7) * 24 + (bid >> 3);
  const int mt  = lin & 15;
  const int nt  = lin >> 4;
  const int z   = nt >> 2;
  const int bm  = mt * 256;
  const int bnz = (nt & 3) * 256;

  const float* bias = (z == 0) ? bq : (z == 1) ? bk : bv;
  short* out = qkv_base + (size_t)z * NTOK * EDIM;

  const int tid = threadIdx.x;
  const int wv  = tid >> 6;
  const int ln  = tid & 63;
  const int q   = ln >> 4;
  const int l16 = ln & 15;
  const int wm  = wv >> 2;
  const int wn  = wv & 3;

  const int sr = tid >> 2;
  const int sc = ((tid & 3) * 16) ^ ((sr & 3) * 16);
  const char* gA0 = xn_i8 + (size_t)(bm + sr) * EDIM + sc;
  const char* gA1 = gA0 + (size_t)128 * EDIM;
  const char* gB0 = w_i8 + ((size_t)z << 20) + (size_t)(bnz + sr) * EDIM + sc;
  const char* gB1 = gB0 + (size_t)128 * EDIM;
  const int wbase = wv * 1024;

#define QSTAGE(tt) do { \
    char* s_ = lds[(tt) & 3]; \
    async16(gA0 + (tt) * 64, s_ + wbase); \
    async16(gA1 + (tt) * 64, s_ + 8192 + wbase); \
    async16(gB0 + (tt) * 64, s_ + 16384 + wbase); \
    async16(gB1 + (tt) * 64, s_ + 24576 + wbase); \
  } while (0)

  const int swz  = (q * 16) ^ ((l16 & 3) * 16);
  const int aoff = (wm * 128 + l16) * 64 + swz;
  const int boff = 16384 + (wn * 64 + l16) * 64 + swz;

  int4v acc[8][4];
#pragma unroll
  for (int mi = 0; mi < 8; ++mi)
#pragma unroll
    for (int ni = 0; ni < 4; ++ni) { int4v zz = {0,0,0,0}; acc[mi][ni] = zz; }

  QSTAGE(0); QSTAGE(1); QSTAGE(2);
  VMCNT(8);
  __builtin_amdgcn_s_barrier();
  __builtin_amdgcn_sched_barrier(0);

#pragma unroll
  for (int t = 0; t < 16; ++t) {
    if (t + 3 < 16) QSTAGE(t + 3);

    const char* sl = lds[t & 3];
    int4v bf[4], af[8];
#pragma unroll
    for (int ni = 0; ni < 4; ++ni)
      bf[ni] = *(const int4v*)(sl + boff + ni * 1024);
#pragma unroll
    for (int mi = 0; mi < 8; ++mi)
      af[mi] = *(const int4v*)(sl + aoff + mi * 1024);

    __builtin_amdgcn_s_setprio(1);
#pragma unroll
    for (int mi = 0; mi < 8; ++mi)
#pragma unroll
      for (int ni = 0; ni < 4; ++ni)
        acc[mi][ni] = __builtin_amdgcn_mfma_i32_16x16x64_i8(
            af[mi], bf[ni], acc[mi][ni], 0, 0, 0);
    __builtin_amdgcn_s_setprio(0);

    if (t < 15) {
      if (t <= 12)      VMCNT(8);
      else if (t == 13) VMCNT(4);
      else              VMCNT(0);
      __builtin_amdgcn_s_barrier();
      __builtin_amdgcn_sched_barrier(0);
    }
  }
#undef QSTAGE

  const int rbase = bm + wm * 128 + q * 4;
  const int cbl   = bnz + wn * 64 + l16;
#pragma unroll
  for (int mi = 0; mi < 8; ++mi) {
    float sa[4];
#pragma unroll
    for (int r = 0; r < 4; ++r) sa[r] = xn_scl[rbase + mi * 16 + r];
#pragma unroll
    for (int ni = 0; ni < 4; ++ni) {
      const int c  = cbl + ni * 16;
      const float sb = w_scl[z * EDIM + c];
      const float bb = bias[c];
      const int4v v = acc[mi][ni];
#pragma unroll
      for (int r = 0; r < 4; ++r)
        out[(size_t)(rbase + mi * 16 + r) * EDIM + c] =
            f2bf((float)v[r] * (sa[r] * sb) + bb);
    }
  }
}

// ---------------------------------------------------------------------------
// O projection, bf16 MFMA, 128x128 tile, ring-of-4 (round-4 K-loop).
// ROUND 9: residual+bias PREFETCH at kernel entry — the 32 scattered 4B
// residual reads are issued oldest-in-queue, complete under the K-loop,
// and the epilogue is pure add+store (no exposed end-of-kernel read
// latency). In-order VMEM completion keeps the counted-vmcnt scheme
// intact (prologue vmcnt(8) additionally drains the residuals).
// Add order preserved: (residual + facc) + bias -> bit-identical output.
// ---------------------------------------------------------------------------
__global__ __launch_bounds__(512, 2) void gemm_o128(
    const short* __restrict__ Abf, const short* __restrict__ Bt,
    const float* __restrict__ bo, const float* __restrict__ residual,
    float* __restrict__ out)
{
  __shared__ __align__(16) char lds[4][32768];   // slot: A @0 (16K), B @16384 (16K)

  const int bid = blockIdx.x;
  const int lin = (bid & 7) * 32 + (bid >> 3);   // 0..255
  const int mt  = lin >> 3;                      // 0..31
  const int nt  = lin & 7;                       // 0..7
  const int bm  = mt * 128;
  const int bn  = nt * 128;

  const int tid = threadIdx.x;
  const int wv  = tid >> 6;
  const int ln  = tid & 63;
  const int quad = ln >> 4;
  const int l16  = ln & 15;
  const int wm  = wv >> 2;       // 0..1  (64-row half)
  const int wn  = wv & 3;        // 0..3  (32-col quarter)

  // ---- prefetch residual + bias for this thread's output elements (oldest
  // in the VMEM queue; retires during the K-loop) ----
  const int r0 = bm + wm * 64 + quad * 4;
  const int c0 = bn + wn * 32 + l16;
  float rsd[4][2][4];
  float bb2[2];
#pragma unroll
  for (int mi = 0; mi < 4; ++mi)
#pragma unroll
    for (int ni = 0; ni < 2; ++ni)
#pragma unroll
      for (int r = 0; r < 4; ++r)
        rsd[mi][ni][r] =
            residual[(size_t)(r0 + mi * 16 + r) * EDIM + c0 + ni * 16];
#pragma unroll
  for (int ni = 0; ni < 2; ++ni) bb2[ni] = bo[c0 + ni * 16];
  asm volatile("" ::: "memory");   // pin issue order: residuals before staging

  const int sr = tid >> 3;                         // 0..63
  const int sc = ((tid & 7) * 16) ^ ((sr & 7) * 16);
  const char* gA0 = (const char*)Abf + (size_t)(bm + sr) * 2048 + sc;
  const char* gA1 = gA0 + (size_t)64 * 2048;
  const char* gB0 = (const char*)Bt  + (size_t)(bn + sr) * 2048 + sc;
  const char* gB1 = gB0 + (size_t)64 * 2048;
  const int wbase = wv * 1024;

#define OSTAGE(tt) do { \
    char* s_ = lds[(tt) & 3]; \
    async16(gA0 + (tt) * 128, s_ + wbase); \
    async16(gA1 + (tt) * 128, s_ + 8192 + wbase); \
    async16(gB0 + (tt) * 128, s_ + 16384 + wbase); \
    async16(gB1 + (tt) * 128, s_ + 24576 + wbase); \
  } while (0)

  int aoff[2], boff[2];
#pragma unroll
  for (int ks = 0; ks < 2; ++ks) {
    const int c = ks * 64 + quad * 16;
    const int s = (l16 & 7) * 16;
    aoff[ks] = (wm * 64 + l16) * 128 + (c ^ s);
    boff[ks] = 16384 + (wn * 32 + l16) * 128 + (c ^ s);
  }

  floatx4 facc[4][2];
#pragma unroll
  for (int mi = 0; mi < 4; ++mi)
#pragma unroll
    for (int ni = 0; ni < 2; ++ni) { floatx4 zz = {0.f,0.f,0.f,0.f}; facc[mi][ni] = zz; }

  OSTAGE(0); OSTAGE(1); OSTAGE(2);
  VMCNT(8);
  __builtin_amdgcn_s_barrier();
  __builtin_amdgcn_sched_barrier(0);

#pragma unroll
  for (int t = 0; t < 16; ++t) {
    if (t + 3 < 16) OSTAGE(t + 3);

    const char* sl = lds[t & 3];
#pragma unroll
    for (int ks = 0; ks < 2; ++ks) {
      short8 af[4], bf[2];
#pragma unroll
      for (int mi = 0; mi < 4; ++mi)
        af[mi] = *(const short8*)(sl + aoff[ks] + mi * 2048);
#pragma unroll
      for (int ni = 0; ni < 2; ++ni)
        bf[ni] = *(const short8*)(sl + boff[ks] + ni * 2048);

      __builtin_amdgcn_s_setprio(1);
#pragma unroll
      for (int mi = 0; mi < 4; ++mi)
#pragma unroll
        for (int ni = 0; ni < 2; ++ni)
          facc[mi][ni] = __builtin_amdgcn_mfma_f32_16x16x32_bf16(
              af[mi], bf[ni], facc[mi][ni], 0, 0, 0);
      __builtin_amdgcn_s_setprio(0);
    }

    if (t < 15) {
      if (t <= 12)      VMCNT(8);
      else if (t == 13) VMCNT(4);
      else              VMCNT(0);
      __builtin_amdgcn_s_barrier();
      __builtin_amdgcn_sched_barrier(0);
    }
  }
#undef OSTAGE

  // ---- epilogue: pure add + store (residual/bias already in registers)
#pragma unroll
  for (int mi = 0; mi < 4; ++mi)
#pragma unroll
    for (int ni = 0; ni < 2; ++ni) {
      const int col = c0 + ni * 16;
#pragma unroll
      for (int r = 0; r < 4; ++r) {
        const int row = r0 + mi * 16 + r;
        out[(size_t)row * EDIM + col] =
            rsd[mi][ni][r] + facc[mi][ni][r] + bb2[ni];
      }
    }
}

// ---------------------------------------------------------------------------
// MFMA attention (bf16 Q/K/V); writes bf16 output rows directly (unchanged).
// ---------------------------------------------------------------------------
#define VT_LD 80
#define PB_LD 40

__global__ __launch_bounds__(256) void attn_mfma(
    const short* __restrict__ Q, const short* __restrict__ K,
    const short* __restrict__ V, short* __restrict__ Obf)
{
  const int tid  = threadIdx.x;
  const int lane = tid & 63;
  const int wave = tid >> 6;
  const int quad = lane >> 4;
  const int l16  = lane & 15;

  const int bh = blockIdx.y;
  const int h  = bh & (NHEAD - 1);
  const int b  = bh >> 4;
  const int s_blk = blockIdx.x * 64;
  const int col0  = h * DHEAD;

  __shared__ __align__(16) short VT[64 * VT_LD];
  __shared__ __align__(16) short Pb[4][16 * PB_LD];

  for (int task = tid; task < 320; task += 256) {
    const int kp  = task >> 3;
    const int dg  = task & 7;
    const int kk0 = kp * 2;
    int sA = s_blk - 15 + kk0;
    int sB = sA + 1;
    if (sA < 0) sA += SLEN;  if (sA >= SLEN) sA -= SLEN;
    if (sB < 0) sB += SLEN;  if (sB >= SLEN) sB -= SLEN;
    const short8 vA = *(const short8*)(V + (size_t)(sA * BSZ + b) * EDIM + col0 + dg * 8);
    const short8 vB = *(const short8*)(V + (size_t)(sB * BSZ + b) * EDIM + col0 + dg * 8);
#pragma unroll
    for (int j = 0; j < 8; ++j) {
      const int d = dg * 8 + j;
      const uint32_t pack = (uint32_t)(uint16_t)vA[j] | ((uint32_t)(uint16_t)vB[j] << 16);
      *(uint32_t*)&VT[d * VT_LD + kk0] = pack;
    }
  }

  const int sw = s_blk + wave * 16;
  short8 aq[2];
  {
    const size_t base = (size_t)((sw + l16) * BSZ + b) * EDIM + col0 + quad * 8;
    aq[0] = *(const short8*)(Q + base);
    aq[1] = *(const short8*)(Q + base + 32);
  }
  short8 bkf[2][2];
#pragma unroll
  for (int T = 0; T < 2; ++T) {
    int ks = sw - 15 + T * 16 + l16;
    if (ks < 0) ks += SLEN;
    if (ks >= SLEN) ks -= SLEN;
    const size_t base = (size_t)(ks * BSZ + b) * EDIM + col0 + quad * 8;
    bkf[T][0] = *(const short8*)(K + base);
    bkf[T][1] = *(const short8*)(K + base + 32);
  }

  floatx4 S[2];
  { floatx4 zz = {0.f, 0.f, 0.f, 0.f}; S[0] = zz; S[1] = zz; }
#pragma unroll
  for (int T = 0; T < 2; ++T) {
    S[T] = __builtin_amdgcn_mfma_f32_16x16x32_bf16(aq[0], bkf[T][0], S[T], 0, 0, 0);
    S[T] = __builtin_amdgcn_mfma_f32_16x16x32_bf16(aq[1], bkf[T][1], S[T], 0, 0, 0);
  }

  float sc[2][4];
#pragma unroll
  for (int T = 0; T < 2; ++T)
#pragma unroll
    for (int r = 0; r < 4; ++r) {
      const int m = quad * 4 + r;
      const int c = T * 16 + l16;
      const int d = c - m;
      sc[T][r] = (d >= 0 && d <= 15) ? S[T][r] * 0.125f : -1e30f;
    }
  float mx[4], sm[4];
#pragma unroll
  for (int r = 0; r < 4; ++r) mx[r] = fmaxf(sc[0][r], sc[1][r]);
#pragma unroll
  for (int off = 1; off <= 8; off <<= 1)
#pragma unroll
    for (int r = 0; r < 4; ++r) mx[r] = fmaxf(mx[r], __shfl_xor(mx[r], off));
  float p[2][4];
#pragma unroll
  for (int r = 0; r < 4; ++r) {
    p[0][r] = __expf(sc[0][r] - mx[r]);
    p[1][r] = __expf(sc[1][r] - mx[r]);
    sm[r] = p[0][r] + p[1][r];
  }
#pragma unroll
  for (int off = 1; off <= 8; off <<= 1)
#pragma unroll
    for (int r = 0; r < 4; ++r) sm[r] += __shfl_xor(sm[r], off);

  __syncthreads();

  short* Pw = Pb[wave];
#pragma unroll
  for (int T = 0; T < 2; ++T)
#pragma unroll
    for (int r = 0; r < 4; ++r) {
      const int m = quad * 4 + r;
      const int c = T * 16 + l16;
      Pw[m * PB_LD + c] = f2bf(p[T][r]);
    }
  __syncthreads();
  const short8 ap = *(const short8*)(Pw + l16 * PB_LD + quad * 8);

  floatx4 Oacc[4];
  { floatx4 zz = {0.f, 0.f, 0.f, 0.f}; Oacc[0] = zz; Oacc[1] = zz; Oacc[2] = zz; Oacc[3] = zz; }
#pragma unroll
  for (int nt = 0; nt < 4; ++nt) {
    const short8 bv = *(const short8*)(VT + (nt * 16 + l16) * VT_LD + wave * 16 + quad * 8);
    Oacc[nt] = __builtin_amdgcn_mfma_f32_16x16x32_bf16(ap, bv, Oacc[nt], 0, 0, 0);
  }

  float ism[4];
#pragma unroll
  for (int r = 0; r < 4; ++r) ism[r] = 1.0f / sm[r];
#pragma unroll
  for (int nt = 0; nt < 4; ++nt)
#pragma unroll
    for (int r = 0; r < 4; ++r) {
      const int m = quad * 4 + r;
      const int row = (sw + m) * BSZ + b;
      Obf[(size_t)row * EDIM + col0 + nt * 16 + l16] = f2bf(Oacc[nt][r] * ism[r]);
    }
}

// ---------------------------------------------------------------------------
extern "C" void kernel_launch(void* const* d_in, const int* in_sizes, int n_in,
                              void* d_out, int out_size, void* d_ws, size_t ws_size,
                              hipStream_t stream) {
  const float* x    = (const float*)d_in[0];
  const float* ln_g = (const float*)d_in[1];
  const float* ln_b = (const float*)d_in[2];
  const float* Wq   = (const float*)d_in[3];
  const float* bq   = (const float*)d_in[4];
  const float* Wk   = (const float*)d_in[5];
  const float* bk   = (const float*)d_in[6];
  const float* Wv   = (const float*)d_in[7];
  const float* bv   = (const float*)d_in[8];
  const float* Wo   = (const float*)d_in[9];
  const float* bo   = (const float*)d_in[10];
  float* out = (float*)d_out;

  char* ws = (char*)d_ws;
  char*  xn_i8   = ws;                                      // 4 MB (dead after qkv)
  short* Wt      = (short*)(ws + ((size_t)4  << 20));       // 8 MB (z3 live to gemm_o)
  char*  w_i8    = ws + ((size_t)12 << 20);                 // 3 MB
  short* QKV     = (short*)(ws + ((size_t)16 << 20));       // 24 MB
  float* xn_scl  = (float*)(ws + ((size_t)44 << 20));       // 16 KB
  float* w_scl   = (float*)(ws + ((size_t)44 << 20) + (1 << 16));
  short* Obf     = (short*)ws;   // 8 MB, overlays xn_i8 + Wt z0/z1 (dead by attn)

  prep_kernel<<<NTOK + 1024, 256, 0, stream>>>(x, ln_g, ln_b, xn_i8, xn_scl,
                                               Wq, Wk, Wv, Wo, Wt);
  quant_w<<<3 * EDIM, 256, 0, stream>>>(Wt, w_i8, w_scl);
  gemm_qkv256<<<192, 512, 0, stream>>>(xn_i8, xn_scl, w_i8, w_scl,
                                       bq, bk, bv, QKV);
  attn_mfma<<<dim3(SLEN / 64, BSZ * NHEAD), 256, 0, stream>>>(
      QKV, QKV + (size_t)NTOK * EDIM, QKV + (size_t)2 * NTOK * EDIM, Obf);
  gemm_o128<<<256, 512, 0, stream>>>(
      Obf, Wt + (size_t)3 * EDIM * EDIM, bo, x, out);
}

// Round 11
// 144.886 us; speedup vs baseline: 1.1091x; 1.0051x over previous
//
#include <hip/hip_runtime.h>
#include <cstdint>
#include <cstddef>

// Problem constants (fixed by reference)
#define SLEN 2048
#define BSZ  2
#define EDIM 1024
#define NHEAD 16
#define DHEAD 64
#define NTOK (SLEN*BSZ)   // 4096

typedef __attribute__((ext_vector_type(8))) short short8;   // 8 x bf16 bits
typedef __attribute__((ext_vector_type(4))) float floatx4;
typedef __attribute__((ext_vector_type(4))) int   int4v;

__device__ __forceinline__ short f2bf(float f) {
  union { float f; uint32_t u; } v; v.f = f;
  uint32_t r = v.u + 0x7fffu + ((v.u >> 16) & 1u);   // round-nearest-even
  return (short)(r >> 16);
}
__device__ __forceinline__ float bf2f(short s) {
  union { uint32_t u; float f; } v; v.u = ((uint32_t)(uint16_t)s) << 16;
  return v.f;
}
__device__ __forceinline__ int q8(float f, float inv) {
  int q = __float2int_rn(f * inv);
  return min(127, max(-127, q));
}
__device__ __forceinline__ void async16(const void* g, void* l) {
  __builtin_amdgcn_global_load_lds((const __attribute__((address_space(1))) void*)g,
                                   (__attribute__((address_space(3))) void*)l,
                                   16, 0, 0);
}
#define VMCNT(n) asm volatile("s_waitcnt vmcnt(" #n ")" ::: "memory")

// ---------------------------------------------------------------------------
// prep: blocks [0,1024): 64x64 weight transpose tiles -> Wt bf16  (HEAD of
//       grid — critical-path producer for quant_w/gemm_qkv starts first).
//       blocks [1024, 1024+NTOK): LayerNorm rows -> int8 + per-row scale.
// (R8 version — validated best)
// ---------------------------------------------------------------------------
__global__ __launch_bounds__(256) void prep_kernel(
    const float* __restrict__ x, const float* __restrict__ g,
    const float* __restrict__ b, char* __restrict__ xn_i8,
    float* __restrict__ xn_scl,
    const float* __restrict__ W0, const float* __restrict__ W1,
    const float* __restrict__ W2, const float* __restrict__ W3,
    short* __restrict__ Wt_base)
{
  const int bid = blockIdx.x;
  const int tid = threadIdx.x;

  if (bid >= 1024) {
    // ---- LayerNorm row ----
    const int row = bid - 1024;
    const float4 v = ((const float4*)(x + (size_t)row * EDIM))[tid];
    float s  = v.x + v.y + v.z + v.w;
    float ss = v.x * v.x + v.y * v.y + v.z * v.z + v.w * v.w;
#pragma unroll
    for (int off = 32; off; off >>= 1) {
      s  += __shfl_xor(s, off);
      ss += __shfl_xor(ss, off);
    }
    __shared__ float ws_s[4], ws_ss[4], ws_m[4];
    const int lane = tid & 63, wave = tid >> 6;
    if (lane == 0) { ws_s[wave] = s; ws_ss[wave] = ss; }
    __syncthreads();
    s  = ws_s[0] + ws_s[1] + ws_s[2] + ws_s[3];
    ss = ws_ss[0] + ws_ss[1] + ws_ss[2] + ws_ss[3];

    const float mean = s * (1.0f / EDIM);
    const float var  = ss * (1.0f / EDIM) - mean * mean;
    const float rs   = rsqrtf(var + 1e-5f);

    const float4 gv = ((const float4*)g)[tid];
    const float4 bv = ((const float4*)b)[tid];
    const float n0 = (v.x - mean) * rs * gv.x + bv.x;
    const float n1 = (v.y - mean) * rs * gv.y + bv.y;
    const float n2 = (v.z - mean) * rs * gv.z + bv.z;
    const float n3 = (v.w - mean) * rs * gv.w + bv.w;

    float am = fmaxf(fmaxf(fabsf(n0), fabsf(n1)), fmaxf(fabsf(n2), fabsf(n3)));
#pragma unroll
    for (int off = 32; off; off >>= 1) am = fmaxf(am, __shfl_xor(am, off));
    if (lane == 0) ws_m[wave] = am;
    __syncthreads();
    am = fmaxf(fmaxf(ws_m[0], ws_m[1]), fmaxf(ws_m[2], ws_m[3]));

    const float inv = (am > 1e-30f) ? 127.0f / am : 0.0f;
    const int q0 = q8(n0, inv), q1 = q8(n1, inv), q2 = q8(n2, inv), q3 = q8(n3, inv);
    const uint32_t pack = (uint32_t)(q0 & 0xff) | ((uint32_t)(q1 & 0xff) << 8) |
                          ((uint32_t)(q2 & 0xff) << 16) | ((uint32_t)(q3 & 0xff) << 24);
    ((uint32_t*)(xn_i8 + (size_t)row * EDIM))[tid] = pack;
    if (tid == 0) xn_scl[row] = am * (1.0f / 127.0f);
  } else {
    // ---- 64x64 transpose tile (grid head) ----
    const int t   = bid;                 // 0..1023
    const int z   = t >> 8;              // 0..3
    const int rem = t & 255;
    const int n0  = (rem & 15) * 64;
    const int k0  = (rem >> 4) * 64;
    const float* W = (z == 0) ? W0 : (z == 1) ? W1 : (z == 2) ? W2 : W3;
    short* Wt = Wt_base + (size_t)z * EDIM * EDIM;

    __shared__ float tile[64][65];       // pad 65: 2-way bank alias (free)
    const int tx = tid & 15;
    const int ty = tid >> 4;             // 0..15
#pragma unroll
    for (int i = 0; i < 4; ++i) {
      const float4 v = *(const float4*)(W + (size_t)(k0 + ty + 16 * i) * EDIM + n0 + tx * 4);
      float* d = &tile[ty + 16 * i][tx * 4];
      d[0] = v.x; d[1] = v.y; d[2] = v.z; d[3] = v.w;
    }
    __syncthreads();
#pragma unroll
    for (int i = 0; i < 4; ++i) {
      short4 s4;
      s4.x = f2bf(tile[tx * 4 + 0][ty + 16 * i]);
      s4.y = f2bf(tile[tx * 4 + 1][ty + 16 * i]);
      s4.z = f2bf(tile[tx * 4 + 2][ty + 16 * i]);
      s4.w = f2bf(tile[tx * 4 + 3][ty + 16 * i]);
      *(short4*)(Wt + (size_t)(n0 + ty + 16 * i) * EDIM + k0 + tx * 4) = s4;
    }
  }
}

// ---------------------------------------------------------------------------
// quant_w: one block per Wt row R (Q,K,V matrices only; Wo stays bf16):
// bf16 -> int8 + per-row (= per output column) scale.
// ---------------------------------------------------------------------------
__global__ __launch_bounds__(256) void quant_w(
    const short* __restrict__ Wt, char* __restrict__ w_i8,
    float* __restrict__ w_scl)
{
  const int R = blockIdx.x;      // 0..3071
  const int tid = threadIdx.x;
  const short4 s4 = ((const short4*)(Wt + (size_t)R * EDIM))[tid];
  const float w0 = bf2f(s4.x), w1 = bf2f(s4.y), w2 = bf2f(s4.z), w3 = bf2f(s4.w);

  float am = fmaxf(fmaxf(fabsf(w0), fabsf(w1)), fmaxf(fabsf(w2), fabsf(w3)));
#pragma unroll
  for (int off = 32; off; off >>= 1) am = fmaxf(am, __shfl_xor(am, off));
  __shared__ float wm[4];
  const int lane = tid & 63, wave = tid >> 6;
  if (lane == 0) wm[wave] = am;
  __syncthreads();
  am = fmaxf(fmaxf(wm[0], wm[1]), fmaxf(wm[2], wm[3]));

  const float inv = (am > 1e-30f) ? 127.0f / am : 0.0f;
  const int q0 = q8(w0, inv), q1 = q8(w1, inv), q2 = q8(w2, inv), q3 = q8(w3, inv);
  const uint32_t pack = (uint32_t)(q0 & 0xff) | ((uint32_t)(q1 & 0xff) << 8) |
                        ((uint32_t)(q2 & 0xff) << 16) | ((uint32_t)(q3 & 0xff) << 24);
  ((uint32_t*)(w_i8 + (size_t)R * EDIM))[tid] = pack;
  if (tid == 0) w_scl[R] = am * (1.0f / 127.0f);
}

// ---------------------------------------------------------------------------
// QKV projection, W8A8 int8, 256x256 tile, ring-of-4 K-tile pipeline.
// ROUND 10: epilogue scale/bias PREFETCH at kernel entry (R9-validated
// lever): 8x float4 xn_scl + 4x w_scl + 4x bias issued oldest-in-queue,
// retire under the K-loop; epilogue becomes pure FMA+pack+store.
// Load movement only — identical values and FP order -> bit-identical.
// ---------------------------------------------------------------------------
__global__ __launch_bounds__(512, 2) void gemm_qkv256(
    const char* __restrict__ xn_i8, const float* __restrict__ xn_scl,
    const char* __restrict__ w_i8, const float* __restrict__ w_scl,
    const float* __restrict__ bq, const float* __restrict__ bk,
    const float* __restrict__ bv, short* __restrict__ qkv_base)
{
  __shared__ __align__(16) char lds[4][32768];   // 128 KiB ring

  const int bid = blockIdx.x;                    // 0..191
  const int lin = (bid & 7) * 24 + (bid >> 3);
  const int mt  = lin & 15;
  const int nt  = lin >> 4;
  const int z   = nt >> 2;
  const int bm  = mt * 256;
  const int bnz = (nt & 3) * 256;

  const float* bias = (z == 0) ? bq : (z == 1) ? bk : bv;
  short* out = qkv_base + (size_t)z * NTOK * EDIM;

  const int tid = threadIdx.x;
  const int wv  = tid >> 6;
  const int ln  = tid & 63;
  const int q   = ln >> 4;
  const int l16 = ln & 15;
  const int wm  = wv >> 2;
  const int wn  = wv & 3;

  // ---- prefetch epilogue scales/bias (oldest in VMEM queue; retire
  // under the K-loop). rbase % 4 == 0 -> float4-aligned xn_scl reads.
  const int rbase = bm + wm * 128 + q * 4;
  const int cbl   = bnz + wn * 64 + l16;
  float4 sa4[8];
#pragma unroll
  for (int mi = 0; mi < 8; ++mi)
    sa4[mi] = *(const float4*)(xn_scl + rbase + mi * 16);
  float sbv[4], bbv[4];
#pragma unroll
  for (int ni = 0; ni < 4; ++ni) {
    sbv[ni] = w_scl[z * EDIM + cbl + ni * 16];
    bbv[ni] = bias[cbl + ni * 16];
  }
  asm volatile("" ::: "memory");   // pin issue order: prefetch before staging

  const int sr = tid >> 2;
  const int sc = ((tid & 3) * 16) ^ ((sr & 3) * 16);
  const char* gA0 = xn_i8 + (size_t)(bm + sr) * EDIM + sc;
  const char* gA1 = gA0 + (size_t)128 * EDIM;
  const char* gB0 = w_i8 + ((size_t)z << 20) + (size_t)(bnz + sr) * EDIM + sc;
  const char* gB1 = gB0 + (size_t)128 * EDIM;
  const int wbase = wv * 1024;

#define QSTAGE(tt) do { \
    char* s_ = lds[(tt) & 3]; \
    async16(gA0 + (tt) * 64, s_ + wbase); \
    async16(gA1 + (tt) * 64, s_ + 8192 + wbase); \
    async16(gB0 + (tt) * 64, s_ + 16384 + wbase); \
    async16(gB1 + (tt) * 64, s_ + 24576 + wbase); \
  } while (0)

  const int swz  = (q * 16) ^ ((l16 & 3) * 16);
  const int aoff = (wm * 128 + l16) * 64 + swz;
  const int boff = 16384 + (wn * 64 + l16) * 64 + swz;

  int4v acc[8][4];
#pragma unroll
  for (int mi = 0; mi < 8; ++mi)
#pragma unroll
    for (int ni = 0; ni < 4; ++ni) { int4v zz = {0,0,0,0}; acc[mi][ni] = zz; }

  QSTAGE(0); QSTAGE(1); QSTAGE(2);
  VMCNT(8);
  __builtin_amdgcn_s_barrier();
  __builtin_amdgcn_sched_barrier(0);

#pragma unroll
  for (int t = 0; t < 16; ++t) {
    if (t + 3 < 16) QSTAGE(t + 3);

    const char* sl = lds[t & 3];
    int4v bf[4], af[8];
#pragma unroll
    for (int ni = 0; ni < 4; ++ni)
      bf[ni] = *(const int4v*)(sl + boff + ni * 1024);
#pragma unroll
    for (int mi = 0; mi < 8; ++mi)
      af[mi] = *(const int4v*)(sl + aoff + mi * 1024);

    __builtin_amdgcn_s_setprio(1);
#pragma unroll
    for (int mi = 0; mi < 8; ++mi)
#pragma unroll
      for (int ni = 0; ni < 4; ++ni)
        acc[mi][ni] = __builtin_amdgcn_mfma_i32_16x16x64_i8(
            af[mi], bf[ni], acc[mi][ni], 0, 0, 0);
    __builtin_amdgcn_s_setprio(0);

    if (t < 15) {
      if (t <= 12)      VMCNT(8);
      else if (t == 13) VMCNT(4);
      else              VMCNT(0);
      __builtin_amdgcn_s_barrier();
      __builtin_amdgcn_sched_barrier(0);
    }
  }
#undef QSTAGE

  // ---- epilogue: pure dequant+pack+store (scales/bias already in regs)
#pragma unroll
  for (int mi = 0; mi < 8; ++mi) {
#pragma unroll
    for (int ni = 0; ni < 4; ++ni) {
      const int c  = cbl + ni * 16;
      const float sb = sbv[ni];
      const float bb = bbv[ni];
      const int4v v = acc[mi][ni];
#pragma unroll
      for (int r = 0; r < 4; ++r)
        out[(size_t)(rbase + mi * 16 + r) * EDIM + c] =
            f2bf((float)v[r] * (sa4[mi][r] * sb) + bb);
    }
  }
}

// ---------------------------------------------------------------------------
// O projection, bf16 MFMA, 128x128 tile, ring-of-4 + residual/bias prefetch
// (R9 version — validated best).
// ---------------------------------------------------------------------------
__global__ __launch_bounds__(512, 2) void gemm_o128(
    const short* __restrict__ Abf, const short* __restrict__ Bt,
    const float* __restrict__ bo, const float* __restrict__ residual,
    float* __restrict__ out)
{
  __shared__ __align__(16) char lds[4][32768];   // slot: A @0 (16K), B @16384 (16K)

  const int bid = blockIdx.x;
  const int lin = (bid & 7) * 32 + (bid >> 3);   // 0..255
  const int mt  = lin >> 3;                      // 0..31
  const int nt  = lin & 7;                       // 0..7
  const int bm  = mt * 128;
  const int bn  = nt * 128;

  const int tid = threadIdx.x;
  const int wv  = tid >> 6;
  const int ln  = tid & 63;
  const int quad = ln >> 4;
  const int l16  = ln & 15;
  const int wm  = wv >> 2;       // 0..1  (64-row half)
  const int wn  = wv & 3;        // 0..3  (32-col quarter)

  // ---- prefetch residual + bias for this thread's output elements (oldest
  // in the VMEM queue; retires during the K-loop) ----
  const int r0 = bm + wm * 64 + quad * 4;
  const int c0 = bn + wn * 32 + l16;
  float rsd[4][2][4];
  float bb2[2];
#pragma unroll
  for (int mi = 0; mi < 4; ++mi)
#pragma unroll
    for (int ni = 0; ni < 2; ++ni)
#pragma unroll
      for (int r = 0; r < 4; ++r)
        rsd[mi][ni][r] =
            residual[(size_t)(r0 + mi * 16 + r) * EDIM + c0 + ni * 16];
#pragma unroll
  for (int ni = 0; ni < 2; ++ni) bb2[ni] = bo[c0 + ni * 16];
  asm volatile("" ::: "memory");   // pin issue order: residuals before staging

  const int sr = tid >> 3;                         // 0..63
  const int sc = ((tid & 7) * 16) ^ ((sr & 7) * 16);
  const char* gA0 = (const char*)Abf + (size_t)(bm + sr) * 2048 + sc;
  const char* gA1 = gA0 + (size_t)64 * 2048;
  const char* gB0 = (const char*)Bt  + (size_t)(bn + sr) * 2048 + sc;
  const char* gB1 = gB0 + (size_t)64 * 2048;
  const int wbase = wv * 1024;

#define OSTAGE(tt) do { \
    char* s_ = lds[(tt) & 3]; \
    async16(gA0 + (tt) * 128, s_ + wbase); \
    async16(gA1 + (tt) * 128, s_ + 8192 + wbase); \
    async16(gB0 + (tt) * 128, s_ + 16384 + wbase); \
    async16(gB1 + (tt) * 128, s_ + 24576 + wbase); \
  } while (0)

  int aoff[2], boff[2];
#pragma unroll
  for (int ks = 0; ks < 2; ++ks) {
    const int c = ks * 64 + quad * 16;
    const int s = (l16 & 7) * 16;
    aoff[ks] = (wm * 64 + l16) * 128 + (c ^ s);
    boff[ks] = 16384 + (wn * 32 + l16) * 128 + (c ^ s);
  }

  floatx4 facc[4][2];
#pragma unroll
  for (int mi = 0; mi < 4; ++mi)
#pragma unroll
    for (int ni = 0; ni < 2; ++ni) { floatx4 zz = {0.f,0.f,0.f,0.f}; facc[mi][ni] = zz; }

  OSTAGE(0); OSTAGE(1); OSTAGE(2);
  VMCNT(8);
  __builtin_amdgcn_s_barrier();
  __builtin_amdgcn_sched_barrier(0);

#pragma unroll
  for (int t = 0; t < 16; ++t) {
    if (t + 3 < 16) OSTAGE(t + 3);

    const char* sl = lds[t & 3];
#pragma unroll
    for (int ks = 0; ks < 2; ++ks) {
      short8 af[4], bf[2];
#pragma unroll
      for (int mi = 0; mi < 4; ++mi)
        af[mi] = *(const short8*)(sl + aoff[ks] + mi * 2048);
#pragma unroll
      for (int ni = 0; ni < 2; ++ni)
        bf[ni] = *(const short8*)(sl + boff[ks] + ni * 2048);

      __builtin_amdgcn_s_setprio(1);
#pragma unroll
      for (int mi = 0; mi < 4; ++mi)
#pragma unroll
        for (int ni = 0; ni < 2; ++ni)
          facc[mi][ni] = __builtin_amdgcn_mfma_f32_16x16x32_bf16(
              af[mi], bf[ni], facc[mi][ni], 0, 0, 0);
      __builtin_amdgcn_s_setprio(0);
    }

    if (t < 15) {
      if (t <= 12)      VMCNT(8);
      else if (t == 13) VMCNT(4);
      else              VMCNT(0);
      __builtin_amdgcn_s_barrier();
      __builtin_amdgcn_sched_barrier(0);
    }
  }
#undef OSTAGE

  // ---- epilogue: pure add + store (residual/bias already in registers)
#pragma unroll
  for (int mi = 0; mi < 4; ++mi)
#pragma unroll
    for (int ni = 0; ni < 2; ++ni) {
      const int col = c0 + ni * 16;
#pragma unroll
      for (int r = 0; r < 4; ++r) {
        const int row = r0 + mi * 16 + r;
        out[(size_t)row * EDIM + col] =
            rsd[mi][ni][r] + facc[mi][ni][r] + bb2[ni];
      }
    }
}

// ---------------------------------------------------------------------------
// MFMA attention (bf16 Q/K/V); writes bf16 output rows directly (unchanged).
// ---------------------------------------------------------------------------
#define VT_LD 80
#define PB_LD 40

__global__ __launch_bounds__(256) void attn_mfma(
    const short* __restrict__ Q, const short* __restrict__ K,
    const short* __restrict__ V, short* __restrict__ Obf)
{
  const int tid  = threadIdx.x;
  const int lane = tid & 63;
  const int wave = tid >> 6;
  const int quad = lane >> 4;
  const int l16  = lane & 15;

  const int bh = blockIdx.y;
  const int h  = bh & (NHEAD - 1);
  const int b  = bh >> 4;
  const int s_blk = blockIdx.x * 64;
  const int col0  = h * DHEAD;

  __shared__ __align__(16) short VT[64 * VT_LD];
  __shared__ __align__(16) short Pb[4][16 * PB_LD];

  for (int task = tid; task < 320; task += 256) {
    const int kp  = task >> 3;
    const int dg  = task & 7;
    const int kk0 = kp * 2;
    int sA = s_blk - 15 + kk0;
    int sB = sA + 1;
    if (sA < 0) sA += SLEN;  if (sA >= SLEN) sA -= SLEN;
    if (sB < 0) sB += SLEN;  if (sB >= SLEN) sB -= SLEN;
    const short8 vA = *(const short8*)(V + (size_t)(sA * BSZ + b) * EDIM + col0 + dg * 8);
    const short8 vB = *(const short8*)(V + (size_t)(sB * BSZ + b) * EDIM + col0 + dg * 8);
#pragma unroll
    for (int j = 0; j < 8; ++j) {
      const int d = dg * 8 + j;
      const uint32_t pack = (uint32_t)(uint16_t)vA[j] | ((uint32_t)(uint16_t)vB[j] << 16);
      *(uint32_t*)&VT[d * VT_LD + kk0] = pack;
    }
  }

  const int sw = s_blk + wave * 16;
  short8 aq[2];
  {
    const size_t base = (size_t)((sw + l16) * BSZ + b) * EDIM + col0 + quad * 8;
    aq[0] = *(const short8*)(Q + base);
    aq[1] = *(const short8*)(Q + base + 32);
  }
  short8 bkf[2][2];
#pragma unroll
  for (int T = 0; T < 2; ++T) {
    int ks = sw - 15 + T * 16 + l16;
    if (ks < 0) ks += SLEN;
    if (ks >= SLEN) ks -= SLEN;
    const size_t base = (size_t)(ks * BSZ + b) * EDIM + col0 + quad * 8;
    bkf[T][0] = *(const short8*)(K + base);
    bkf[T][1] = *(const short8*)(K + base + 32);
  }

  floatx4 S[2];
  { floatx4 zz = {0.f, 0.f, 0.f, 0.f}; S[0] = zz; S[1] = zz; }
#pragma unroll
  for (int T = 0; T < 2; ++T) {
    S[T] = __builtin_amdgcn_mfma_f32_16x16x32_bf16(aq[0], bkf[T][0], S[T], 0, 0, 0);
    S[T] = __builtin_amdgcn_mfma_f32_16x16x32_bf16(aq[1], bkf[T][1], S[T], 0, 0, 0);
  }

  float sc[2][4];
#pragma unroll
  for (int T = 0; T < 2; ++T)
#pragma unroll
    for (int r = 0; r < 4; ++r) {
      const int m = quad * 4 + r;
      const int c = T * 16 + l16;
      const int d = c - m;
      sc[T][r] = (d >= 0 && d <= 15) ? S[T][r] * 0.125f : -1e30f;
    }
  float mx[4], sm[4];
#pragma unroll
  for (int r = 0; r < 4; ++r) mx[r] = fmaxf(sc[0][r], sc[1][r]);
#pragma unroll
  for (int off = 1; off <= 8; off <<= 1)
#pragma unroll
    for (int r = 0; r < 4; ++r) mx[r] = fmaxf(mx[r], __shfl_xor(mx[r], off));
  float p[2][4];
#pragma unroll
  for (int r = 0; r < 4; ++r) {
    p[0][r] = __expf(sc[0][r] - mx[r]);
    p[1][r] = __expf(sc[1][r] - mx[r]);
    sm[r] = p[0][r] + p[1][r];
  }
#pragma unroll
  for (int off = 1; off <= 8; off <<= 1)
#pragma unroll
    for (int r = 0; r < 4; ++r) sm[r] += __shfl_xor(sm[r], off);

  __syncthreads();

  short* Pw = Pb[wave];
#pragma unroll
  for (int T = 0; T < 2; ++T)
#pragma unroll
    for (int r = 0; r < 4; ++r) {
      const int m = quad * 4 + r;
      const int c = T * 16 + l16;
      Pw[m * PB_LD + c] = f2bf(p[T][r]);
    }
  __syncthreads();
  const short8 ap = *(const short8*)(Pw + l16 * PB_LD + quad * 8);

  floatx4 Oacc[4];
  { floatx4 zz = {0.f, 0.f, 0.f, 0.f}; Oacc[0] = zz; Oacc[1] = zz; Oacc[2] = zz; Oacc[3] = zz; }
#pragma unroll
  for (int nt = 0; nt < 4; ++nt) {
    const short8 bv = *(const short8*)(VT + (nt * 16 + l16) * VT_LD + wave * 16 + quad * 8);
    Oacc[nt] = __builtin_amdgcn_mfma_f32_16x16x32_bf16(ap, bv, Oacc[nt], 0, 0, 0);
  }

  float ism[4];
#pragma unroll
  for (int r = 0; r < 4; ++r) ism[r] = 1.0f / sm[r];
#pragma unroll
  for (int nt = 0; nt < 4; ++nt)
#pragma unroll
    for (int r = 0; r < 4; ++r) {
      const int m = quad * 4 + r;
      const int row = (sw + m) * BSZ + b;
      Obf[(size_t)row * EDIM + col0 + nt * 16 + l16] = f2bf(Oacc[nt][r] * ism[r]);
    }
}

// ---------------------------------------------------------------------------
extern "C" void kernel_launch(void* const* d_in, const int* in_sizes, int n_in,
                              void* d_out, int out_size, void* d_ws, size_t ws_size,
                              hipStream_t stream) {
  const float* x    = (const float*)d_in[0];
  const float* ln_g = (const float*)d_in[1];
  const float* ln_b = (const float*)d_in[2];
  const float* Wq   = (const float*)d_in[3];
  const float* bq   = (const float*)d_in[4];
  const float* Wk   = (const float*)d_in[5];
  const float* bk   = (const float*)d_in[6];
  const float* Wv   = (const float*)d_in[7];
  const float* bv   = (const float*)d_in[8];
  const float* Wo   = (const float*)d_in[9];
  const float* bo   = (const float*)d_in[10];
  float* out = (float*)d_out;

  char* ws = (char*)d_ws;
  char*  xn_i8   = ws;                                      // 4 MB (dead after qkv)
  short* Wt      = (short*)(ws + ((size_t)4  << 20));       // 8 MB (z3 live to gemm_o)
  char*  w_i8    = ws + ((size_t)12 << 20);                 // 3 MB
  short* QKV     = (short*)(ws + ((size_t)16 << 20));       // 24 MB
  float* xn_scl  = (float*)(ws + ((size_t)44 << 20));       // 16 KB
  float* w_scl   = (float*)(ws + ((size_t)44 << 20) + (1 << 16));
  short* Obf     = (short*)ws;   // 8 MB, overlays xn_i8 + Wt z0/z1 (dead by attn)

  prep_kernel<<<NTOK + 1024, 256, 0, stream>>>(x, ln_g, ln_b, xn_i8, xn_scl,
                                               Wq, Wk, Wv, Wo, Wt);
  quant_w<<<3 * EDIM, 256, 0, stream>>>(Wt, w_i8, w_scl);
  gemm_qkv256<<<192, 512, 0, stream>>>(xn_i8, xn_scl, w_i8, w_scl,
                                       bq, bk, bv, QKV);
  attn_mfma<<<dim3(SLEN / 64, BSZ * NHEAD), 256, 0, stream>>>(
      QKV, QKV + (size_t)NTOK * EDIM, QKV + (size_t)2 * NTOK * EDIM, Obf);
  gemm_o128<<<256, 512, 0, stream>>>(
      Obf, Wt + (size_t)3 * EDIM * EDIM, bo, x, out);
}